// Round 10
// baseline (300.856 us; speedup 1.0000x reference)
//
#include <hip/hip_runtime.h>

#define N 4096

__device__ __forceinline__ void load_A(const float* __restrict__ Ag,
                                       float Ac[3][3], float& inv)
{
#pragma unroll
    for (int i = 0; i < 9; ++i) Ac[i / 3][i % 3] = Ag[i];
    inv = 1.0f / Ac[1][1];
    Ac[1][1] = 0.f;
}

__device__ __forceinline__ void make_w44(const float Ac[3][3], float wt[4][4])
{
#pragma unroll
    for (int a = 0; a < 4; ++a)
#pragma unroll
        for (int b = 0; b < 4; ++b) wt[a][b] = 0.f;
#pragma unroll
    for (int r = 0; r < 2; ++r)
#pragma unroll
        for (int c = 0; c < 2; ++c)
#pragma unroll
            for (int i = 0; i < 3; ++i)
#pragma unroll
                for (int j = 0; j < 3; ++j) wt[r + i][c + j] += Ac[i][j];
}

// Branch-free u_bc row segment, 4-wide: lane covers cols xm..xm+3 + L/R scalars.
__device__ __forceinline__ void load_row6(const float* __restrict__ u,
                                          int gy, int xm, int colL, int colR,
                                          bool cornL, bool cornR, bool yedge,
                                          float v[6])
{
    int cy = min(max(gy, 0), N - 1);
    const float* rowp = &u[(size_t)cy * N];
    float4 m = *(const float4*)&rowp[xm];
    float L = rowp[colL];
    float R = rowp[colR];
    if (yedge) {
        bool oob = (gy < 0) | (gy >= N);
        if (oob & cornL) L = 0.f;
        if (oob & cornR) R = 0.f;
    }
    v[0] = L; v[1] = m.x; v[2] = m.y; v[3] = m.z; v[4] = m.w; v[5] = R;
}

// 8-wide variant: cols xm..xm+7 (two aligned float4) + L/R scalars.
__device__ __forceinline__ void load_row10(const float* __restrict__ u,
                                           int gy, int xm, int colL, int colR,
                                           bool cornL, bool cornR, bool yedge,
                                           float v[10])
{
    int cy = min(max(gy, 0), N - 1);
    const float* rowp = &u[(size_t)cy * N];
    float4 m0 = *(const float4*)&rowp[xm];
    float4 m1 = *(const float4*)&rowp[xm + 4];
    float L = rowp[colL];
    float R = rowp[colR];
    if (yedge) {
        bool oob = (gy < 0) | (gy >= N);
        if (oob & cornL) L = 0.f;
        if (oob & cornR) R = 0.f;
    }
    v[0] = L;
    v[1] = m0.x; v[2] = m0.y; v[3] = m0.z; v[4] = m0.w;
    v[5] = m1.x; v[6] = m1.y; v[7] = m1.z; v[8] = m1.w;
    v[9] = R;
}

// ---- fused smooth+restrict+restrict -> r2, plus tree r3..r7, one kernel ----
// Grid (32,32), 512 threads. Thread: 2 r2 cells (Y2, X2..X2+1) from 6x10 u window.
__global__ __launch_bounds__(512) void smoothtree_kernel(
    const float* __restrict__ u, const float* __restrict__ Ag,
    float* __restrict__ r2, float* __restrict__ r3, float* __restrict__ r4,
    float* __restrict__ r5, float* __restrict__ r6, float* __restrict__ r7)
{
    int t = threadIdx.x;
    int BX = blockIdx.x, BY = blockIdx.y;
    __shared__ float s2[32][33];
    __shared__ float s3[16][17];
    __shared__ float s4[8][9];
    __shared__ float s5[4][5];
    __shared__ float s6[2][3];
    float Ac[3][3], inv;
    load_A(Ag, Ac, inv);
    float wt[4][4];
    make_w44(Ac, wt);

    int ly = t >> 4, lx = t & 15;          // r2 tile coords: row ly, cols 2lx..2lx+1
    int Y2 = 32 * BY + ly;
    int X2 = 32 * BX + 2 * lx;
    int gy0 = 4 * Y2 - 1;                  // 6 u rows: gy0..gy0+5
    bool yedge = (gy0 < 0) | (gy0 + 5 >= N);
    int xm = 4 * X2;                       // u cols xm-1 .. xm+8
    int colL = max(xm - 1, 0), colR = min(xm + 8, N - 1);
    bool cornL = (xm - 1 < 0), cornR = (xm + 8 >= N);
    float v[6][10];
#pragma unroll
    for (int r = 0; r < 6; ++r)
        load_row10(u, gy0 + r, xm, colL, colR, cornL, cornR, yedge, v[r]);

    // r1 block 2x4 (rows 2Y2..2Y2+1, cols 2X2..2X2+3), then r2 pair
    float r1[2][4];
#pragma unroll
    for (int a = 0; a < 2; ++a)
#pragma unroll
        for (int b = 0; b < 4; ++b) {
            float s = 0.f;
#pragma unroll
            for (int i = 0; i < 4; ++i)
#pragma unroll
                for (int j = 0; j < 4; ++j)
                    s += wt[i][j] * v[2 * a + i][2 * b + j];
            r1[a][b] = 0.25f * s;
        }
    float2 o;
    o.x = 0.25f * (r1[0][0] + r1[0][1] + r1[1][0] + r1[1][1]);
    o.y = 0.25f * (r1[0][2] + r1[0][3] + r1[1][2] + r1[1][3]);
    *(float2*)&r2[(size_t)Y2 * 1024 + X2] = o;
    s2[ly][2 * lx] = o.x;
    s2[ly][2 * lx + 1] = o.y;
    __syncthreads();

    if (t < 256) {
        int y = t >> 4, x = t & 15;
        float vv = 0.25f * (s2[2 * y][2 * x] + s2[2 * y][2 * x + 1] +
                            s2[2 * y + 1][2 * x] + s2[2 * y + 1][2 * x + 1]);
        r3[(size_t)(16 * BY + y) * 512 + 16 * BX + x] = vv;
        s3[y][x] = vv;
    }
    __syncthreads();
    if (t < 64) {
        int y = t >> 3, x = t & 7;
        float vv = 0.25f * (s3[2 * y][2 * x] + s3[2 * y][2 * x + 1] +
                            s3[2 * y + 1][2 * x] + s3[2 * y + 1][2 * x + 1]);
        r4[(size_t)(8 * BY + y) * 256 + 8 * BX + x] = vv;
        s4[y][x] = vv;
    }
    __syncthreads();
    if (t < 16) {
        int y = t >> 2, x = t & 3;
        float vv = 0.25f * (s4[2 * y][2 * x] + s4[2 * y][2 * x + 1] +
                            s4[2 * y + 1][2 * x] + s4[2 * y + 1][2 * x + 1]);
        r5[(size_t)(4 * BY + y) * 128 + 4 * BX + x] = vv;
        s5[y][x] = vv;
    }
    __syncthreads();
    if (t < 4) {
        int y = t >> 1, x = t & 1;
        float vv = 0.25f * (s5[2 * y][2 * x] + s5[2 * y][2 * x + 1] +
                            s5[2 * y + 1][2 * x] + s5[2 * y + 1][2 * x + 1]);
        r6[(size_t)(2 * BY + y) * 64 + 2 * BX + x] = vv;
        s6[y][x] = vv;
    }
    __syncthreads();
    if (t == 0) {
        r7[(size_t)BY * 32 + BX] =
            0.25f * (s6[0][0] + s6[0][1] + s6[1][0] + s6[1][1]);
    }
}

// ---- fused coarse up-chain: r7..r3 -> e@512 ----
__global__ __launch_bounds__(256) void coarse_up_kernel(
    const float* __restrict__ r7, const float* __restrict__ r6,
    const float* __restrict__ r5, const float* __restrict__ r4,
    const float* __restrict__ r3, const float* __restrict__ Ag,
    float* __restrict__ e512)
{
    int bx = blockIdx.x, by = blockIdx.y;
    int t = threadIdx.x;
    __shared__ float s7[32][33];
    __shared__ float s64[64][65];
    __shared__ float s128[11][12];
    __shared__ float s256[18][19];
    float Ac[3][3], inv;
    load_A(Ag, Ac, inv);
    for (int i = t; i < 1024; i += 256) s7[i >> 5][i & 31] = r7[i] * inv;
    __syncthreads();
    for (int i = t; i < 4096; i += 256) {
        int y = i >> 6, x = i & 63;
        float ctr = s7[y >> 1][x >> 1];
        float sm = 0.f;
#pragma unroll
        for (int dy = -1; dy <= 1; ++dy)
#pragma unroll
            for (int dx = -1; dx <= 1; ++dx) {
                if (dy == 0 && dx == 0) continue;
                int yy = y + dy, xx = x + dx;
                float pe = 0.f;
                if (yy >= 0 && yy < 64 && xx >= 0 && xx < 64) pe = s7[yy >> 1][xx >> 1];
                sm += Ac[dy + 1][dx + 1] * pe;
            }
        s64[y][x] = ctr - sm * inv + r6[i] * inv;
    }
    __syncthreads();
    int R1 = 8 * by - 2, C1 = 8 * bx - 2;
    if (t < 121) {
        int pr = t / 11, pc = t % 11;
        int gy = R1 + pr, gx = C1 + pc;
        if (gy >= 0 && gy < 128 && gx >= 0 && gx < 128) {
            float ctr = s64[gy >> 1][gx >> 1];
            float sm = 0.f;
#pragma unroll
            for (int dy = -1; dy <= 1; ++dy)
#pragma unroll
                for (int dx = -1; dx <= 1; ++dx) {
                    if (dy == 0 && dx == 0) continue;
                    int yy = gy + dy, xx = gx + dx;
                    float pe = 0.f;
                    if (yy >= 0 && yy < 128 && xx >= 0 && xx < 128) pe = s64[yy >> 1][xx >> 1];
                    sm += Ac[dy + 1][dx + 1] * pe;
                }
            s128[pr][pc] = ctr - sm * inv + r5[(size_t)gy * 128 + gx] * inv;
        }
    }
    __syncthreads();
    int R2l = 16 * by - 1, C2l = 16 * bx - 1;
    for (int i = t; i < 324; i += 256) {
        int pr = i / 18, pc = i % 18;
        int gy = R2l + pr, gx = C2l + pc;
        if (gy >= 0 && gy < 256 && gx >= 0 && gx < 256) {
            float ctr = s128[(gy >> 1) - R1][(gx >> 1) - C1];
            float sm = 0.f;
#pragma unroll
            for (int dy = -1; dy <= 1; ++dy)
#pragma unroll
                for (int dx = -1; dx <= 1; ++dx) {
                    if (dy == 0 && dx == 0) continue;
                    int yy = gy + dy, xx = gx + dx;
                    float pe = 0.f;
                    if (yy >= 0 && yy < 256 && xx >= 0 && xx < 256)
                        pe = s128[(yy >> 1) - R1][(xx >> 1) - C1];
                    sm += Ac[dy + 1][dx + 1] * pe;
                }
            s256[pr][pc] = ctr - sm * inv + r4[(size_t)gy * 256 + gx] * inv;
        }
    }
    __syncthreads();
#pragma unroll
    for (int k = 0; k < 4; ++k) {
        int idx = t + 256 * k;
        int y = 32 * by + (idx >> 5), x = 32 * bx + (idx & 31);
        float ctr = s256[(y >> 1) - R2l][(x >> 1) - C2l];
        float sm = 0.f;
#pragma unroll
        for (int dy = -1; dy <= 1; ++dy)
#pragma unroll
            for (int dx = -1; dx <= 1; ++dx) {
                if (dy == 0 && dx == 0) continue;
                int yy = y + dy, xx = x + dx;
                float pe = 0.f;
                if (yy >= 0 && yy < 512 && xx >= 0 && xx < 512)
                    pe = s256[(yy >> 1) - R2l][(xx >> 1) - C2l];
                sm += Ac[dy + 1][dx + 1] * pe;
            }
        e512[(size_t)y * 512 + x] = ctr - sm * inv + r3[(size_t)y * 512 + x] * inv;
    }
}

// ---- fused: e512 -> e1024 (LDS) -> e2048 (regs, r1 recomputed) -> u update ----
// Block: 256 thr = 4 waves; u tile 256 cols x 32 rows. Grid (16,128). (round-8 version)
template <bool WANTMM>
__global__ __launch_bounds__(256) void final_fused_kernel(
    const float* __restrict__ u, const float* __restrict__ e512,
    const float* __restrict__ r2, const float* __restrict__ Ag,
    float* __restrict__ uo, float* __restrict__ partials)
{
    const int n = N;
    int t = threadIdx.x, lane = t & 63, w = t >> 6;
    int bx = blockIdx.x, by = blockIdx.y;
    int x0 = 256 * bx, y0 = 32 * by;
    __shared__ float s512v[6][36];
    __shared__ float s1024[10][68];
    float Ac[3][3], inv;
    load_A(Ag, Ac, inv);
    float wt[4][4];
    make_w44(Ac, wt);

    int yb = y0 + 8 * w;
    int gy0 = yb - 1;
    bool yedge = (gy0 < 0) | (gy0 + 9 >= n);
    int xm = x0 + 4 * lane;
    int colL = max(xm - 1, 0), colR = min(xm + 4, n - 1);
    bool cornL = (xm - 1 < 0), cornR = (xm + 4 >= n);
    float v[10][6];
#pragma unroll
    for (int rr = 0; rr < 10; ++rr)
        load_row6(u, gy0 + rr, xm, colL, colR, cornL, cornR, yedge, v[rr]);

    int S5r = 4 * by - 1, S5c = 32 * bx - 1;
    if (t < 216) {
        int pr = t / 36, pc = t - (t / 36) * 36;
        int gy = S5r + pr, gx = S5c + pc;
        float vv = 0.f;
        if (pc < 34 && gy >= 0 && gy < 512 && gx >= 0 && gx < 512)
            vv = e512[(size_t)gy * 512 + gx];
        s512v[pr][pc] = vv;
    }
    __syncthreads();
    int R10 = 8 * by - 1, C10 = 64 * bx - 1;
    for (int i = t; i < 680; i += 256) {
        int pr = i / 68, pc = i - (i / 68) * 68;
        if (pc < 66) {
            int gy = R10 + pr, gx = C10 + pc;
            float val = 0.f;
            if (gy >= 0 && gy < 1024 && gx >= 0 && gx < 1024) {
                float ctr = s512v[(gy >> 1) - S5r][(gx >> 1) - S5c];
                float sm = 0.f;
#pragma unroll
                for (int dy = -1; dy <= 1; ++dy)
#pragma unroll
                    for (int dx = -1; dx <= 1; ++dx) {
                        if (dy == 0 && dx == 0) continue;
                        sm += Ac[dy + 1][dx + 1] *
                              s512v[((gy + dy) >> 1) - S5r][((gx + dx) >> 1) - S5c];
                    }
                val = ctr - sm * inv + r2[(size_t)gy * 1024 + gx] * inv;
            }
            s1024[pr][pc] = val;
        }
    }
    __syncthreads();
    float e2[4][2];
    int EY0 = 16 * by + 4 * w, EX0 = 128 * bx + 2 * lane;
#pragma unroll
    for (int a = 0; a < 4; ++a) {
        int gy = EY0 + a;
        float a0 = 0.f, a1 = 0.f;
#pragma unroll
        for (int i = 0; i < 4; ++i) {
            const float* vv = v[2 * a + i];
#pragma unroll
            for (int j = 0; j < 4; ++j) {
                a0 += wt[i][j] * vv[j];
                a1 += wt[i][j] * vv[j + 2];
            }
        }
        float r1v[2] = {0.25f * a0, 0.25f * a1};
#pragma unroll
        for (int b = 0; b < 2; ++b) {
            int gx = EX0 + b;
            float ctr = s1024[(gy >> 1) - R10][(gx >> 1) - C10];
            float sm = 0.f;
#pragma unroll
            for (int dy = -1; dy <= 1; ++dy)
#pragma unroll
                for (int dx = -1; dx <= 1; ++dx) {
                    if (dy == 0 && dx == 0) continue;
                    sm += Ac[dy + 1][dx + 1] *
                          s1024[((gy + dy) >> 1) - R10][((gx + dx) >> 1) - C10];
                }
            e2[a][b] = ctr - sm * inv + r1v[b] * inv;
        }
    }
    float mn = 3.402823466e+38f, mx = -3.402823466e+38f;
#pragma unroll
    for (int r = 0; r < 8; ++r) {
        int y = yb + r;
        const float* va = v[r];
        const float* vb = v[r + 1];
        const float* vc = v[r + 2];
        float out[4];
#pragma unroll
        for (int c = 0; c < 4; ++c) {
            float sm = Ac[0][0] * va[c] + Ac[0][1] * va[c + 1] + Ac[0][2] * va[c + 2]
                     + Ac[1][0] * vb[c]                        + Ac[1][2] * vb[c + 2]
                     + Ac[2][0] * vc[c] + Ac[2][1] * vc[c + 1] + Ac[2][2] * vc[c + 2];
            out[c] = vb[c + 1] - e2[r >> 1][c >> 1] - sm * inv;
        }
        *(float4*)&uo[(size_t)y * n + xm] =
            make_float4(out[0], out[1], out[2], out[3]);
        if (WANTMM) {
            mn = fminf(mn, fminf(fminf(out[0], out[1]), fminf(out[2], out[3])));
            mx = fmaxf(mx, fmaxf(fmaxf(out[0], out[1]), fmaxf(out[2], out[3])));
        }
    }
    if (WANTMM) {
#pragma unroll
        for (int off = 32; off > 0; off >>= 1) {
            mn = fminf(mn, __shfl_down(mn, off));
            mx = fmaxf(mx, __shfl_down(mx, off));
        }
        __shared__ float smn[4], smx[4];
        if (lane == 0) { smn[w] = mn; smx[w] = mx; }
        __syncthreads();
        if (t == 0) {
            mn = smn[0]; mx = smx[0];
            for (int wq = 1; wq < 4; ++wq) { mn = fminf(mn, smn[wq]); mx = fmaxf(mx, smx[wq]); }
            int bid = by * 16 + bx;
            partials[2 * bid] = mn;
            partials[2 * bid + 1] = mx;
        }
    }
}

__global__ __launch_bounds__(1024) void minmax_final_kernel(
    const float* __restrict__ partials, float* __restrict__ mm)
{
    float mn = 3.402823466e+38f, mx = -3.402823466e+38f;
    for (int i = threadIdx.x; i < 2048; i += 1024) {
        mn = fminf(mn, partials[2 * i]);
        mx = fmaxf(mx, partials[2 * i + 1]);
    }
#pragma unroll
    for (int off = 32; off > 0; off >>= 1) {
        mn = fminf(mn, __shfl_down(mn, off));
        mx = fmaxf(mx, __shfl_down(mx, off));
    }
    __shared__ float smn[16], smx[16];
    int lane = threadIdx.x & 63, wv = threadIdx.x >> 6;
    if (lane == 0) { smn[wv] = mn; smx[wv] = mx; }
    __syncthreads();
    if (threadIdx.x == 0) {
        mn = smn[0]; mx = smx[0];
        for (int w = 1; w < 16; ++w) { mn = fminf(mn, smn[w]); mx = fmaxf(mx, smx[w]); }
        mm[0] = mn;
        mm[1] = mx;
    }
}

__global__ __launch_bounds__(256) void normalize_kernel(
    float* __restrict__ u, const float* __restrict__ mm)
{
    size_t i = ((size_t)blockIdx.x * 256 + threadIdx.x) * 4;
    float mn = mm[0];
    float sc = 1.0f / (mm[1] - mm[0]);
    float4 v = *(float4*)&u[i];
    v.x = (v.x - mn) * sc;
    v.y = (v.y - mn) * sc;
    v.z = (v.z - mn) * sc;
    v.w = (v.w - mn) * sc;
    *(float4*)&u[i] = v;
}

extern "C" void kernel_launch(void* const* d_in, const int* in_sizes, int n_in,
                              void* d_out, int out_size, void* d_ws, size_t ws_size,
                              hipStream_t stream)
{
    const float* A  = (const float*)d_in[0];
    const float* u0 = (const float*)d_in[1];
    float* uout = (float*)d_out;
    float* ws = (float*)d_ws;

    size_t off = 0;
    float* r2 = ws + off; off += 1024ull * 1024;
    float* r3 = ws + off; off += 512ull * 512;
    float* r4 = ws + off; off += 256ull * 256;
    float* r5 = ws + off; off += 128ull * 128;
    float* r6 = ws + off; off += 64ull * 64;
    float* r7 = ws + off; off += 32ull * 32;
    float* e5 = ws + off; off += 512ull * 512;
    float* uA = ws + off; off += 4096ull * 4096;
    float* partials = ws + off; off += 4096;
    float* mm = ws + off; off += 2;

    for (int it = 0; it < 4; ++it) {
        const float* us = (it == 0) ? u0 : ((it == 2) ? uout : uA);
        float* dst = (it & 1) ? uout : uA;
        smoothtree_kernel<<<dim3(32, 32), 512, 0, stream>>>(us, A, r2, r3, r4, r5, r6, r7);
        coarse_up_kernel<<<dim3(16, 16), 256, 0, stream>>>(r7, r6, r5, r4, r3, A, e5);
        if (it == 3)
            final_fused_kernel<true><<<dim3(16, 128), 256, 0, stream>>>(
                us, e5, r2, A, dst, partials);
        else
            final_fused_kernel<false><<<dim3(16, 128), 256, 0, stream>>>(
                us, e5, r2, A, dst, partials);
    }
    minmax_final_kernel<<<1, 1024, 0, stream>>>(partials, mm);
    normalize_kernel<<<16384, 256, 0, stream>>>(uout, mm);
}

// Round 11
// 262.983 us; speedup vs baseline: 1.1440x; 1.1440x over previous
//
#include <hip/hip_runtime.h>

#define N 4096

__device__ __forceinline__ void load_A(const float* __restrict__ Ag,
                                       float Ac[3][3], float& inv)
{
#pragma unroll
    for (int i = 0; i < 9; ++i) Ac[i / 3][i % 3] = Ag[i];
    inv = 1.0f / Ac[1][1];
    Ac[1][1] = 0.f;
}

__device__ __forceinline__ void make_w44(const float Ac[3][3], float wt[4][4])
{
#pragma unroll
    for (int a = 0; a < 4; ++a)
#pragma unroll
        for (int b = 0; b < 4; ++b) wt[a][b] = 0.f;
#pragma unroll
    for (int r = 0; r < 2; ++r)
#pragma unroll
        for (int c = 0; c < 2; ++c)
#pragma unroll
            for (int i = 0; i < 3; ++i)
#pragma unroll
                for (int j = 0; j < 3; ++j) wt[r + i][c + j] += Ac[i][j];
}

// Branch-free u_bc row segment: lane covers cols xm..xm+3 (aligned float4),
// plus L (xm-1) and R (xm+4) via clamped scalar loads.
__device__ __forceinline__ void load_row6(const float* __restrict__ u,
                                          int gy, int xm, int colL, int colR,
                                          bool cornL, bool cornR, bool yedge,
                                          float v[6])
{
    int cy = min(max(gy, 0), N - 1);
    const float* rowp = &u[(size_t)cy * N];
    float4 m = *(const float4*)&rowp[xm];
    float L = rowp[colL];
    float R = rowp[colR];
    if (yedge) {
        bool oob = (gy < 0) | (gy >= N);
        if (oob & cornL) L = 0.f;
        if (oob & cornR) R = 0.f;
    }
    v[0] = L; v[1] = m.x; v[2] = m.y; v[3] = m.z; v[4] = m.w; v[5] = R;
}

// XCD-aware bijective swizzle for 2048-block 1D grids (2048 % 8 == 0).
__device__ __forceinline__ void swz2048(int bid, int& bx, int& by)
{
    int reg = (bid & 7) * 256 + (bid >> 3);
    bx = reg & 15;
    by = reg >> 4;
}

// ---- fused smooth(bc(u)) + restrict + restrict -> r2 (1024^2) + r3 (512^2) ----
// Wave: 4 r1 rows x 128 r1 cols (in regs) -> 2 r2 rows x 64 r2 cols. 2048 blocks.
__global__ __launch_bounds__(256) void smooth_restrict2_kernel(
    const float* __restrict__ u, const float* __restrict__ Ag,
    float* __restrict__ r2, float* __restrict__ r3)
{
    int t = threadIdx.x, lane = t & 63, w = t >> 6;
    int bx, by;
    swz2048(blockIdx.x, bx, by);
    int x0 = 256 * bx;
    int Y0 = 16 * by + 4 * w;          // first r1 row of this wave
    int gy0 = 2 * Y0 - 1;
    bool yedge = (gy0 < 0) | (gy0 + 9 >= N);
    float Ac[3][3], inv;
    load_A(Ag, Ac, inv);
    float wt[4][4];
    make_w44(Ac, wt);

    int xm = x0 + 4 * lane;
    int colL = max(xm - 1, 0), colR = min(xm + 4, N - 1);
    bool cornL = (xm - 1 < 0), cornR = (xm + 4 >= N);
    float v[10][6];
#pragma unroll
    for (int rr = 0; rr < 10; ++rr)
        load_row6(u, gy0 + rr, xm, colL, colR, cornL, cornR, yedge, v[rr]);

    float o0[4], o1[4];
#pragma unroll
    for (int q = 0; q < 4; ++q) {
        float a0 = 0.f, a1 = 0.f;
#pragma unroll
        for (int a = 0; a < 4; ++a) {
            const float* vv = v[2 * q + a];
#pragma unroll
            for (int b = 0; b < 4; ++b) {
                a0 += wt[a][b] * vv[b];
                a1 += wt[a][b] * vv[b + 2];
            }
        }
        o0[q] = 0.25f * a0;
        o1[q] = 0.25f * a1;
    }
    int Y2 = Y0 >> 1, X2 = 64 * bx + lane;   // Y2 even
    float val0 = 0.25f * (o0[0] + o1[0] + o0[1] + o1[1]);
    float val1 = 0.25f * (o0[2] + o1[2] + o0[3] + o1[3]);
    r2[(size_t)Y2 * 1024 + X2] = val0;
    r2[(size_t)(Y2 + 1) * 1024 + X2] = val1;
    // r3 via horizontal lane pair (vertical pair already in this thread)
    float s0 = val0 + val1;
    float s1 = __shfl_xor(s0, 1);
    if (!(lane & 1))
        r3[(size_t)(Y2 >> 1) * 512 + (X2 >> 1)] = 0.25f * (s0 + s1);
}

// ---- restriction tree: r3 -> r4..r7 (grid 16x16) ----
__global__ __launch_bounds__(256) void multirestrict_kernel(
    const float* __restrict__ r3, float* __restrict__ r4, float* __restrict__ r5,
    float* __restrict__ r6, float* __restrict__ r7)
{
    int BX = blockIdx.x, BY = blockIdx.y;
    __shared__ float s4[16][17];
    __shared__ float s5[8][9];
    __shared__ float s6[4][5];
    int t = threadIdx.x;
    {
        int y = t >> 4, x = t & 15;
        const float* b0 = &r3[(size_t)(32 * BY + 2 * y) * 512 + 32 * BX + 2 * x];
        float2 a = *(const float2*)b0;
        float2 b = *(const float2*)(b0 + 512);
        float vv = 0.25f * (a.x + a.y + b.x + b.y);
        r4[(size_t)(16 * BY + y) * 256 + 16 * BX + x] = vv;
        s4[y][x] = vv;
    }
    __syncthreads();
    if (t < 64) {
        int y = t >> 3, x = t & 7;
        float vv = 0.25f * (s4[2 * y][2 * x] + s4[2 * y][2 * x + 1] +
                            s4[2 * y + 1][2 * x] + s4[2 * y + 1][2 * x + 1]);
        r5[(size_t)(8 * BY + y) * 128 + 8 * BX + x] = vv;
        s5[y][x] = vv;
    }
    __syncthreads();
    if (t < 16) {
        int y = t >> 2, x = t & 3;
        float vv = 0.25f * (s5[2 * y][2 * x] + s5[2 * y][2 * x + 1] +
                            s5[2 * y + 1][2 * x] + s5[2 * y + 1][2 * x + 1]);
        r6[(size_t)(4 * BY + y) * 64 + 4 * BX + x] = vv;
        s6[y][x] = vv;
    }
    __syncthreads();
    if (t < 4) {
        int y = t >> 1, x = t & 1;
        float vv = 0.25f * (s6[2 * y][2 * x] + s6[2 * y][2 * x + 1] +
                            s6[2 * y + 1][2 * x] + s6[2 * y + 1][2 * x + 1]);
        r7[(size_t)(2 * BY + y) * 32 + 2 * BX + x] = vv;
    }
}

// ---- fused coarse up-chain: r7..r3 -> e@512 ----
__global__ __launch_bounds__(256) void coarse_up_kernel(
    const float* __restrict__ r7, const float* __restrict__ r6,
    const float* __restrict__ r5, const float* __restrict__ r4,
    const float* __restrict__ r3, const float* __restrict__ Ag,
    float* __restrict__ e512)
{
    int bx = blockIdx.x, by = blockIdx.y;
    int t = threadIdx.x;
    __shared__ float s7[32][33];
    __shared__ float s64[64][65];
    __shared__ float s128[11][12];
    __shared__ float s256[18][19];
    float Ac[3][3], inv;
    load_A(Ag, Ac, inv);
    for (int i = t; i < 1024; i += 256) s7[i >> 5][i & 31] = r7[i] * inv;
    __syncthreads();
    for (int i = t; i < 4096; i += 256) {
        int y = i >> 6, x = i & 63;
        float ctr = s7[y >> 1][x >> 1];
        float sm = 0.f;
#pragma unroll
        for (int dy = -1; dy <= 1; ++dy)
#pragma unroll
            for (int dx = -1; dx <= 1; ++dx) {
                if (dy == 0 && dx == 0) continue;
                int yy = y + dy, xx = x + dx;
                float pe = 0.f;
                if (yy >= 0 && yy < 64 && xx >= 0 && xx < 64) pe = s7[yy >> 1][xx >> 1];
                sm += Ac[dy + 1][dx + 1] * pe;
            }
        s64[y][x] = ctr - sm * inv + r6[i] * inv;
    }
    __syncthreads();
    int R1 = 8 * by - 2, C1 = 8 * bx - 2;
    if (t < 121) {
        int pr = t / 11, pc = t % 11;
        int gy = R1 + pr, gx = C1 + pc;
        if (gy >= 0 && gy < 128 && gx >= 0 && gx < 128) {
            float ctr = s64[gy >> 1][gx >> 1];
            float sm = 0.f;
#pragma unroll
            for (int dy = -1; dy <= 1; ++dy)
#pragma unroll
                for (int dx = -1; dx <= 1; ++dx) {
                    if (dy == 0 && dx == 0) continue;
                    int yy = gy + dy, xx = gx + dx;
                    float pe = 0.f;
                    if (yy >= 0 && yy < 128 && xx >= 0 && xx < 128) pe = s64[yy >> 1][xx >> 1];
                    sm += Ac[dy + 1][dx + 1] * pe;
                }
            s128[pr][pc] = ctr - sm * inv + r5[(size_t)gy * 128 + gx] * inv;
        }
    }
    __syncthreads();
    int R2l = 16 * by - 1, C2l = 16 * bx - 1;
    for (int i = t; i < 324; i += 256) {
        int pr = i / 18, pc = i % 18;
        int gy = R2l + pr, gx = C2l + pc;
        if (gy >= 0 && gy < 256 && gx >= 0 && gx < 256) {
            float ctr = s128[(gy >> 1) - R1][(gx >> 1) - C1];
            float sm = 0.f;
#pragma unroll
            for (int dy = -1; dy <= 1; ++dy)
#pragma unroll
                for (int dx = -1; dx <= 1; ++dx) {
                    if (dy == 0 && dx == 0) continue;
                    int yy = gy + dy, xx = gx + dx;
                    float pe = 0.f;
                    if (yy >= 0 && yy < 256 && xx >= 0 && xx < 256)
                        pe = s128[(yy >> 1) - R1][(xx >> 1) - C1];
                    sm += Ac[dy + 1][dx + 1] * pe;
                }
            s256[pr][pc] = ctr - sm * inv + r4[(size_t)gy * 256 + gx] * inv;
        }
    }
    __syncthreads();
#pragma unroll
    for (int k = 0; k < 4; ++k) {
        int idx = t + 256 * k;
        int y = 32 * by + (idx >> 5), x = 32 * bx + (idx & 31);
        float ctr = s256[(y >> 1) - R2l][(x >> 1) - C2l];
        float sm = 0.f;
#pragma unroll
        for (int dy = -1; dy <= 1; ++dy)
#pragma unroll
            for (int dx = -1; dx <= 1; ++dx) {
                if (dy == 0 && dx == 0) continue;
                int yy = y + dy, xx = x + dx;
                float pe = 0.f;
                if (yy >= 0 && yy < 512 && xx >= 0 && xx < 512)
                    pe = s256[(yy >> 1) - R2l][(xx >> 1) - C2l];
                sm += Ac[dy + 1][dx + 1] * pe;
            }
        e512[(size_t)y * 512 + x] = ctr - sm * inv + r3[(size_t)y * 512 + x] * inv;
    }
}

// ---- fused: e512 -> e1024 (LDS) -> e2048 (regs, r1 recomputed) -> u update ----
// Block: 256 thr = 4 waves; u tile 256 cols x 32 rows. 2048 blocks (swizzled).
template <bool WANTMM>
__global__ __launch_bounds__(256) void final_fused_kernel(
    const float* __restrict__ u, const float* __restrict__ e512,
    const float* __restrict__ r2, const float* __restrict__ Ag,
    float* __restrict__ uo, float* __restrict__ partials)
{
    const int n = N;
    int t = threadIdx.x, lane = t & 63, w = t >> 6;
    int bx, by;
    swz2048(blockIdx.x, bx, by);
    int x0 = 256 * bx, y0 = 32 * by;
    __shared__ float s512v[6][36];
    __shared__ float s1024[10][68];
    float Ac[3][3], inv;
    load_A(Ag, Ac, inv);
    float wt[4][4];
    make_w44(Ac, wt);

    int yb = y0 + 8 * w;
    int gy0 = yb - 1;
    bool yedge = (gy0 < 0) | (gy0 + 9 >= n);
    int xm = x0 + 4 * lane;
    int colL = max(xm - 1, 0), colR = min(xm + 4, n - 1);
    bool cornL = (xm - 1 < 0), cornR = (xm + 4 >= n);
    float v[10][6];
#pragma unroll
    for (int rr = 0; rr < 10; ++rr)
        load_row6(u, gy0 + rr, xm, colL, colR, cornL, cornR, yedge, v[rr]);

    int S5r = 4 * by - 1, S5c = 32 * bx - 1;
    if (t < 216) {
        int pr = t / 36, pc = t - (t / 36) * 36;
        int gy = S5r + pr, gx = S5c + pc;
        float vv = 0.f;
        if (pc < 34 && gy >= 0 && gy < 512 && gx >= 0 && gx < 512)
            vv = e512[(size_t)gy * 512 + gx];
        s512v[pr][pc] = vv;
    }
    __syncthreads();
    int R10 = 8 * by - 1, C10 = 64 * bx - 1;
    for (int i = t; i < 680; i += 256) {
        int pr = i / 68, pc = i - (i / 68) * 68;
        if (pc < 66) {
            int gy = R10 + pr, gx = C10 + pc;
            float val = 0.f;
            if (gy >= 0 && gy < 1024 && gx >= 0 && gx < 1024) {
                float ctr = s512v[(gy >> 1) - S5r][(gx >> 1) - S5c];
                float sm = 0.f;
#pragma unroll
                for (int dy = -1; dy <= 1; ++dy)
#pragma unroll
                    for (int dx = -1; dx <= 1; ++dx) {
                        if (dy == 0 && dx == 0) continue;
                        sm += Ac[dy + 1][dx + 1] *
                              s512v[((gy + dy) >> 1) - S5r][((gx + dx) >> 1) - S5c];
                    }
                val = ctr - sm * inv + r2[(size_t)gy * 1024 + gx] * inv;
            }
            s1024[pr][pc] = val;
        }
    }
    __syncthreads();
    float e2[4][2];
    int EY0 = 16 * by + 4 * w, EX0 = 128 * bx + 2 * lane;
#pragma unroll
    for (int a = 0; a < 4; ++a) {
        int gy = EY0 + a;
        float a0 = 0.f, a1 = 0.f;
#pragma unroll
        for (int i = 0; i < 4; ++i) {
            const float* vv = v[2 * a + i];
#pragma unroll
            for (int j = 0; j < 4; ++j) {
                a0 += wt[i][j] * vv[j];
                a1 += wt[i][j] * vv[j + 2];
            }
        }
        float r1v[2] = {0.25f * a0, 0.25f * a1};
#pragma unroll
        for (int b = 0; b < 2; ++b) {
            int gx = EX0 + b;
            float ctr = s1024[(gy >> 1) - R10][(gx >> 1) - C10];
            float sm = 0.f;
#pragma unroll
            for (int dy = -1; dy <= 1; ++dy)
#pragma unroll
                for (int dx = -1; dx <= 1; ++dx) {
                    if (dy == 0 && dx == 0) continue;
                    sm += Ac[dy + 1][dx + 1] *
                          s1024[((gy + dy) >> 1) - R10][((gx + dx) >> 1) - C10];
                }
            e2[a][b] = ctr - sm * inv + r1v[b] * inv;
        }
    }
    float mn = 3.402823466e+38f, mx = -3.402823466e+38f;
#pragma unroll
    for (int r = 0; r < 8; ++r) {
        int y = yb + r;
        const float* va = v[r];
        const float* vb = v[r + 1];
        const float* vc = v[r + 2];
        float out[4];
#pragma unroll
        for (int c = 0; c < 4; ++c) {
            float sm = Ac[0][0] * va[c] + Ac[0][1] * va[c + 1] + Ac[0][2] * va[c + 2]
                     + Ac[1][0] * vb[c]                        + Ac[1][2] * vb[c + 2]
                     + Ac[2][0] * vc[c] + Ac[2][1] * vc[c + 1] + Ac[2][2] * vc[c + 2];
            out[c] = vb[c + 1] - e2[r >> 1][c >> 1] - sm * inv;
        }
        *(float4*)&uo[(size_t)y * n + xm] =
            make_float4(out[0], out[1], out[2], out[3]);
        if (WANTMM) {
            mn = fminf(mn, fminf(fminf(out[0], out[1]), fminf(out[2], out[3])));
            mx = fmaxf(mx, fmaxf(fmaxf(out[0], out[1]), fmaxf(out[2], out[3])));
        }
    }
    if (WANTMM) {
#pragma unroll
        for (int off = 32; off > 0; off >>= 1) {
            mn = fminf(mn, __shfl_down(mn, off));
            mx = fmaxf(mx, __shfl_down(mx, off));
        }
        __shared__ float smn[4], smx[4];
        if (lane == 0) { smn[w] = mn; smx[w] = mx; }
        __syncthreads();
        if (t == 0) {
            mn = smn[0]; mx = smx[0];
            for (int wq = 1; wq < 4; ++wq) { mn = fminf(mn, smn[wq]); mx = fmaxf(mx, smx[wq]); }
            int bid = by * 16 + bx;
            partials[2 * bid] = mn;
            partials[2 * bid + 1] = mx;
        }
    }
}

__global__ __launch_bounds__(1024) void minmax_final_kernel(
    const float* __restrict__ partials, float* __restrict__ mm)
{
    float mn = 3.402823466e+38f, mx = -3.402823466e+38f;
    for (int i = threadIdx.x; i < 2048; i += 1024) {
        mn = fminf(mn, partials[2 * i]);
        mx = fmaxf(mx, partials[2 * i + 1]);
    }
#pragma unroll
    for (int off = 32; off > 0; off >>= 1) {
        mn = fminf(mn, __shfl_down(mn, off));
        mx = fmaxf(mx, __shfl_down(mx, off));
    }
    __shared__ float smn[16], smx[16];
    int lane = threadIdx.x & 63, wv = threadIdx.x >> 6;
    if (lane == 0) { smn[wv] = mn; smx[wv] = mx; }
    __syncthreads();
    if (threadIdx.x == 0) {
        mn = smn[0]; mx = smx[0];
        for (int w = 1; w < 16; ++w) { mn = fminf(mn, smn[w]); mx = fmaxf(mx, smx[w]); }
        mm[0] = mn;
        mm[1] = mx;
    }
}

__global__ __launch_bounds__(256) void normalize_kernel(
    float* __restrict__ u, const float* __restrict__ mm)
{
    size_t i = ((size_t)blockIdx.x * 256 + threadIdx.x) * 4;
    float mn = mm[0];
    float sc = 1.0f / (mm[1] - mm[0]);
    float4 v = *(float4*)&u[i];
    v.x = (v.x - mn) * sc;
    v.y = (v.y - mn) * sc;
    v.z = (v.z - mn) * sc;
    v.w = (v.w - mn) * sc;
    *(float4*)&u[i] = v;
}

extern "C" void kernel_launch(void* const* d_in, const int* in_sizes, int n_in,
                              void* d_out, int out_size, void* d_ws, size_t ws_size,
                              hipStream_t stream)
{
    const float* A  = (const float*)d_in[0];
    const float* u0 = (const float*)d_in[1];
    float* uout = (float*)d_out;
    float* ws = (float*)d_ws;

    size_t off = 0;
    float* r2 = ws + off; off += 1024ull * 1024;
    float* r3 = ws + off; off += 512ull * 512;
    float* r4 = ws + off; off += 256ull * 256;
    float* r5 = ws + off; off += 128ull * 128;
    float* r6 = ws + off; off += 64ull * 64;
    float* r7 = ws + off; off += 32ull * 32;
    float* e5 = ws + off; off += 512ull * 512;
    float* uA = ws + off; off += 4096ull * 4096;
    float* partials = ws + off; off += 4096;
    float* mm = ws + off; off += 2;

    for (int it = 0; it < 4; ++it) {
        const float* us = (it == 0) ? u0 : ((it == 2) ? uout : uA);
        float* dst = (it & 1) ? uout : uA;
        smooth_restrict2_kernel<<<2048, 256, 0, stream>>>(us, A, r2, r3);
        multirestrict_kernel<<<dim3(16, 16), 256, 0, stream>>>(r3, r4, r5, r6, r7);
        coarse_up_kernel<<<dim3(16, 16), 256, 0, stream>>>(r7, r6, r5, r4, r3, A, e5);
        if (it == 3)
            final_fused_kernel<true><<<2048, 256, 0, stream>>>(
                us, e5, r2, A, dst, partials);
        else
            final_fused_kernel<false><<<2048, 256, 0, stream>>>(
                us, e5, r2, A, dst, partials);
    }
    minmax_final_kernel<<<1, 1024, 0, stream>>>(partials, mm);
    normalize_kernel<<<16384, 256, 0, stream>>>(uout, mm);
}

// Round 12
// 216.533 us; speedup vs baseline: 1.3894x; 1.2145x over previous
//
#include <hip/hip_runtime.h>

#define N 4096

__device__ __forceinline__ float bf2f(unsigned short h)
{
    unsigned int u = ((unsigned int)h) << 16;
    return __uint_as_float(u);
}
__device__ __forceinline__ unsigned short f2bf(float f)
{
    unsigned int x = __float_as_uint(f);
    unsigned int r = (x + 0x7FFFu + ((x >> 16) & 1u)) >> 16;  // round-nearest-even
    return (unsigned short)r;
}

__device__ __forceinline__ void load_A(const float* __restrict__ Ag,
                                       float Ac[3][3], float& inv)
{
#pragma unroll
    for (int i = 0; i < 9; ++i) Ac[i / 3][i % 3] = Ag[i];
    inv = 1.0f / Ac[1][1];
    Ac[1][1] = 0.f;
}

__device__ __forceinline__ void make_w44(const float Ac[3][3], float wt[4][4])
{
#pragma unroll
    for (int a = 0; a < 4; ++a)
#pragma unroll
        for (int b = 0; b < 4; ++b) wt[a][b] = 0.f;
#pragma unroll
    for (int r = 0; r < 2; ++r)
#pragma unroll
        for (int c = 0; c < 2; ++c)
#pragma unroll
            for (int i = 0; i < 3; ++i)
#pragma unroll
                for (int j = 0; j < 3; ++j) wt[r + i][c + j] += Ac[i][j];
}

// Branch-free u_bc row segment (f32 or bf16 storage; math in f32).
template <typename TI>
__device__ __forceinline__ void load_row6T(const TI* __restrict__ u,
                                           int gy, int xm, int colL, int colR,
                                           bool cornL, bool cornR, bool yedge,
                                           float v[6])
{
    int cy = min(max(gy, 0), N - 1);
    const TI* rowp = &u[(size_t)cy * N];
    float L, R;
    if constexpr (sizeof(TI) == 4) {
        float4 m = *(const float4*)&rowp[xm];
        v[1] = m.x; v[2] = m.y; v[3] = m.z; v[4] = m.w;
        L = rowp[colL];
        R = rowp[colR];
    } else {
        ushort4 m = *(const ushort4*)&rowp[xm];
        v[1] = bf2f(m.x); v[2] = bf2f(m.y); v[3] = bf2f(m.z); v[4] = bf2f(m.w);
        L = bf2f(rowp[colL]);
        R = bf2f(rowp[colR]);
    }
    if (yedge) {
        bool oob = (gy < 0) | (gy >= N);
        if (oob & cornL) L = 0.f;
        if (oob & cornR) R = 0.f;
    }
    v[0] = L; v[5] = R;
}

// XCD-aware bijective swizzle for 2048-block 1D grids (2048 % 8 == 0).
__device__ __forceinline__ void swz2048(int bid, int& bx, int& by)
{
    int reg = (bid & 7) * 256 + (bid >> 3);
    bx = reg & 15;
    by = reg >> 4;
}

// ---- fused smooth(bc(u)) + restrict + restrict -> r2 (1024^2) + r3 (512^2) ----
template <typename TI>
__global__ __launch_bounds__(256) void smooth_restrict2_kernel(
    const TI* __restrict__ u, const float* __restrict__ Ag,
    float* __restrict__ r2, float* __restrict__ r3)
{
    int t = threadIdx.x, lane = t & 63, w = t >> 6;
    int bx, by;
    swz2048(blockIdx.x, bx, by);
    int x0 = 256 * bx;
    int Y0 = 16 * by + 4 * w;
    int gy0 = 2 * Y0 - 1;
    bool yedge = (gy0 < 0) | (gy0 + 9 >= N);
    float Ac[3][3], inv;
    load_A(Ag, Ac, inv);
    float wt[4][4];
    make_w44(Ac, wt);

    int xm = x0 + 4 * lane;
    int colL = max(xm - 1, 0), colR = min(xm + 4, N - 1);
    bool cornL = (xm - 1 < 0), cornR = (xm + 4 >= N);
    float v[10][6];
#pragma unroll
    for (int rr = 0; rr < 10; ++rr)
        load_row6T<TI>(u, gy0 + rr, xm, colL, colR, cornL, cornR, yedge, v[rr]);

    float o0[4], o1[4];
#pragma unroll
    for (int q = 0; q < 4; ++q) {
        float a0 = 0.f, a1 = 0.f;
#pragma unroll
        for (int a = 0; a < 4; ++a) {
            const float* vv = v[2 * q + a];
#pragma unroll
            for (int b = 0; b < 4; ++b) {
                a0 += wt[a][b] * vv[b];
                a1 += wt[a][b] * vv[b + 2];
            }
        }
        o0[q] = 0.25f * a0;
        o1[q] = 0.25f * a1;
    }
    int Y2 = Y0 >> 1, X2 = 64 * bx + lane;   // Y2 even
    float val0 = 0.25f * (o0[0] + o1[0] + o0[1] + o1[1]);
    float val1 = 0.25f * (o0[2] + o1[2] + o0[3] + o1[3]);
    r2[(size_t)Y2 * 1024 + X2] = val0;
    r2[(size_t)(Y2 + 1) * 1024 + X2] = val1;
    float s0 = val0 + val1;
    float s1 = __shfl_xor(s0, 1);
    if (!(lane & 1))
        r3[(size_t)(Y2 >> 1) * 512 + (X2 >> 1)] = 0.25f * (s0 + s1);
}

// ---- restriction tree: r3 -> r4..r7 (grid 16x16) ----
__global__ __launch_bounds__(256) void multirestrict_kernel(
    const float* __restrict__ r3, float* __restrict__ r4, float* __restrict__ r5,
    float* __restrict__ r6, float* __restrict__ r7)
{
    int BX = blockIdx.x, BY = blockIdx.y;
    __shared__ float s4[16][17];
    __shared__ float s5[8][9];
    __shared__ float s6[4][5];
    int t = threadIdx.x;
    {
        int y = t >> 4, x = t & 15;
        const float* b0 = &r3[(size_t)(32 * BY + 2 * y) * 512 + 32 * BX + 2 * x];
        float2 a = *(const float2*)b0;
        float2 b = *(const float2*)(b0 + 512);
        float vv = 0.25f * (a.x + a.y + b.x + b.y);
        r4[(size_t)(16 * BY + y) * 256 + 16 * BX + x] = vv;
        s4[y][x] = vv;
    }
    __syncthreads();
    if (t < 64) {
        int y = t >> 3, x = t & 7;
        float vv = 0.25f * (s4[2 * y][2 * x] + s4[2 * y][2 * x + 1] +
                            s4[2 * y + 1][2 * x] + s4[2 * y + 1][2 * x + 1]);
        r5[(size_t)(8 * BY + y) * 128 + 8 * BX + x] = vv;
        s5[y][x] = vv;
    }
    __syncthreads();
    if (t < 16) {
        int y = t >> 2, x = t & 3;
        float vv = 0.25f * (s5[2 * y][2 * x] + s5[2 * y][2 * x + 1] +
                            s5[2 * y + 1][2 * x] + s5[2 * y + 1][2 * x + 1]);
        r6[(size_t)(4 * BY + y) * 64 + 4 * BX + x] = vv;
        s6[y][x] = vv;
    }
    __syncthreads();
    if (t < 4) {
        int y = t >> 1, x = t & 1;
        float vv = 0.25f * (s6[2 * y][2 * x] + s6[2 * y][2 * x + 1] +
                            s6[2 * y + 1][2 * x] + s6[2 * y + 1][2 * x + 1]);
        r7[(size_t)(2 * BY + y) * 32 + 2 * BX + x] = vv;
    }
}

// ---- fused coarse up-chain: r7..r3 -> e@512 ----
__global__ __launch_bounds__(256) void coarse_up_kernel(
    const float* __restrict__ r7, const float* __restrict__ r6,
    const float* __restrict__ r5, const float* __restrict__ r4,
    const float* __restrict__ r3, const float* __restrict__ Ag,
    float* __restrict__ e512)
{
    int bx = blockIdx.x, by = blockIdx.y;
    int t = threadIdx.x;
    __shared__ float s7[32][33];
    __shared__ float s64[64][65];
    __shared__ float s128[11][12];
    __shared__ float s256[18][19];
    float Ac[3][3], inv;
    load_A(Ag, Ac, inv);
    for (int i = t; i < 1024; i += 256) s7[i >> 5][i & 31] = r7[i] * inv;
    __syncthreads();
    for (int i = t; i < 4096; i += 256) {
        int y = i >> 6, x = i & 63;
        float ctr = s7[y >> 1][x >> 1];
        float sm = 0.f;
#pragma unroll
        for (int dy = -1; dy <= 1; ++dy)
#pragma unroll
            for (int dx = -1; dx <= 1; ++dx) {
                if (dy == 0 && dx == 0) continue;
                int yy = y + dy, xx = x + dx;
                float pe = 0.f;
                if (yy >= 0 && yy < 64 && xx >= 0 && xx < 64) pe = s7[yy >> 1][xx >> 1];
                sm += Ac[dy + 1][dx + 1] * pe;
            }
        s64[y][x] = ctr - sm * inv + r6[i] * inv;
    }
    __syncthreads();
    int R1 = 8 * by - 2, C1 = 8 * bx - 2;
    if (t < 121) {
        int pr = t / 11, pc = t % 11;
        int gy = R1 + pr, gx = C1 + pc;
        if (gy >= 0 && gy < 128 && gx >= 0 && gx < 128) {
            float ctr = s64[gy >> 1][gx >> 1];
            float sm = 0.f;
#pragma unroll
            for (int dy = -1; dy <= 1; ++dy)
#pragma unroll
                for (int dx = -1; dx <= 1; ++dx) {
                    if (dy == 0 && dx == 0) continue;
                    int yy = gy + dy, xx = gx + dx;
                    float pe = 0.f;
                    if (yy >= 0 && yy < 128 && xx >= 0 && xx < 128) pe = s64[yy >> 1][xx >> 1];
                    sm += Ac[dy + 1][dx + 1] * pe;
                }
            s128[pr][pc] = ctr - sm * inv + r5[(size_t)gy * 128 + gx] * inv;
        }
    }
    __syncthreads();
    int R2l = 16 * by - 1, C2l = 16 * bx - 1;
    for (int i = t; i < 324; i += 256) {
        int pr = i / 18, pc = i % 18;
        int gy = R2l + pr, gx = C2l + pc;
        if (gy >= 0 && gy < 256 && gx >= 0 && gx < 256) {
            float ctr = s128[(gy >> 1) - R1][(gx >> 1) - C1];
            float sm = 0.f;
#pragma unroll
            for (int dy = -1; dy <= 1; ++dy)
#pragma unroll
                for (int dx = -1; dx <= 1; ++dx) {
                    if (dy == 0 && dx == 0) continue;
                    int yy = gy + dy, xx = gx + dx;
                    float pe = 0.f;
                    if (yy >= 0 && yy < 256 && xx >= 0 && xx < 256)
                        pe = s128[(yy >> 1) - R1][(xx >> 1) - C1];
                    sm += Ac[dy + 1][dx + 1] * pe;
                }
            s256[pr][pc] = ctr - sm * inv + r4[(size_t)gy * 256 + gx] * inv;
        }
    }
    __syncthreads();
#pragma unroll
    for (int k = 0; k < 4; ++k) {
        int idx = t + 256 * k;
        int y = 32 * by + (idx >> 5), x = 32 * bx + (idx & 31);
        float ctr = s256[(y >> 1) - R2l][(x >> 1) - C2l];
        float sm = 0.f;
#pragma unroll
        for (int dy = -1; dy <= 1; ++dy)
#pragma unroll
            for (int dx = -1; dx <= 1; ++dx) {
                if (dy == 0 && dx == 0) continue;
                int yy = y + dy, xx = x + dx;
                float pe = 0.f;
                if (yy >= 0 && yy < 512 && xx >= 0 && xx < 512)
                    pe = s256[(yy >> 1) - R2l][(xx >> 1) - C2l];
                sm += Ac[dy + 1][dx + 1] * pe;
            }
        e512[(size_t)y * 512 + x] = ctr - sm * inv + r3[(size_t)y * 512 + x] * inv;
    }
}

// ---- fused: e512 -> e1024 (LDS) -> e2048 (regs, r1 recomputed) -> u update ----
// TI/TO: float or ushort(bf16) storage for u_in / u_out.
template <typename TI, typename TO, bool WANTMM>
__global__ __launch_bounds__(256) void final_fused_kernel(
    const TI* __restrict__ u, const float* __restrict__ e512,
    const float* __restrict__ r2, const float* __restrict__ Ag,
    TO* __restrict__ uo, float* __restrict__ partials)
{
    const int n = N;
    int t = threadIdx.x, lane = t & 63, w = t >> 6;
    int bx, by;
    swz2048(blockIdx.x, bx, by);
    int x0 = 256 * bx, y0 = 32 * by;
    __shared__ float s512v[6][36];
    __shared__ float s1024[10][68];
    float Ac[3][3], inv;
    load_A(Ag, Ac, inv);
    float wt[4][4];
    make_w44(Ac, wt);

    int yb = y0 + 8 * w;
    int gy0 = yb - 1;
    bool yedge = (gy0 < 0) | (gy0 + 9 >= n);
    int xm = x0 + 4 * lane;
    int colL = max(xm - 1, 0), colR = min(xm + 4, n - 1);
    bool cornL = (xm - 1 < 0), cornR = (xm + 4 >= n);
    float v[10][6];
#pragma unroll
    for (int rr = 0; rr < 10; ++rr)
        load_row6T<TI>(u, gy0 + rr, xm, colL, colR, cornL, cornR, yedge, v[rr]);

    int S5r = 4 * by - 1, S5c = 32 * bx - 1;
    if (t < 216) {
        int pr = t / 36, pc = t - (t / 36) * 36;
        int gy = S5r + pr, gx = S5c + pc;
        float vv = 0.f;
        if (pc < 34 && gy >= 0 && gy < 512 && gx >= 0 && gx < 512)
            vv = e512[(size_t)gy * 512 + gx];
        s512v[pr][pc] = vv;
    }
    __syncthreads();
    int R10 = 8 * by - 1, C10 = 64 * bx - 1;
    for (int i = t; i < 680; i += 256) {
        int pr = i / 68, pc = i - (i / 68) * 68;
        if (pc < 66) {
            int gy = R10 + pr, gx = C10 + pc;
            float val = 0.f;
            if (gy >= 0 && gy < 1024 && gx >= 0 && gx < 1024) {
                float ctr = s512v[(gy >> 1) - S5r][(gx >> 1) - S5c];
                float sm = 0.f;
#pragma unroll
                for (int dy = -1; dy <= 1; ++dy)
#pragma unroll
                    for (int dx = -1; dx <= 1; ++dx) {
                        if (dy == 0 && dx == 0) continue;
                        sm += Ac[dy + 1][dx + 1] *
                              s512v[((gy + dy) >> 1) - S5r][((gx + dx) >> 1) - S5c];
                    }
                val = ctr - sm * inv + r2[(size_t)gy * 1024 + gx] * inv;
            }
            s1024[pr][pc] = val;
        }
    }
    __syncthreads();
    float e2[4][2];
    int EY0 = 16 * by + 4 * w, EX0 = 128 * bx + 2 * lane;
#pragma unroll
    for (int a = 0; a < 4; ++a) {
        int gy = EY0 + a;
        float a0 = 0.f, a1 = 0.f;
#pragma unroll
        for (int i = 0; i < 4; ++i) {
            const float* vv = v[2 * a + i];
#pragma unroll
            for (int j = 0; j < 4; ++j) {
                a0 += wt[i][j] * vv[j];
                a1 += wt[i][j] * vv[j + 2];
            }
        }
        float r1v[2] = {0.25f * a0, 0.25f * a1};
#pragma unroll
        for (int b = 0; b < 2; ++b) {
            int gx = EX0 + b;
            float ctr = s1024[(gy >> 1) - R10][(gx >> 1) - C10];
            float sm = 0.f;
#pragma unroll
            for (int dy = -1; dy <= 1; ++dy)
#pragma unroll
                for (int dx = -1; dx <= 1; ++dx) {
                    if (dy == 0 && dx == 0) continue;
                    sm += Ac[dy + 1][dx + 1] *
                          s1024[((gy + dy) >> 1) - R10][((gx + dx) >> 1) - C10];
                }
            e2[a][b] = ctr - sm * inv + r1v[b] * inv;
        }
    }
    float mn = 3.402823466e+38f, mx = -3.402823466e+38f;
#pragma unroll
    for (int r = 0; r < 8; ++r) {
        int y = yb + r;
        const float* va = v[r];
        const float* vb = v[r + 1];
        const float* vc = v[r + 2];
        float out[4];
#pragma unroll
        for (int c = 0; c < 4; ++c) {
            float sm = Ac[0][0] * va[c] + Ac[0][1] * va[c + 1] + Ac[0][2] * va[c + 2]
                     + Ac[1][0] * vb[c]                        + Ac[1][2] * vb[c + 2]
                     + Ac[2][0] * vc[c] + Ac[2][1] * vc[c + 1] + Ac[2][2] * vc[c + 2];
            out[c] = vb[c + 1] - e2[r >> 1][c >> 1] - sm * inv;
        }
        if constexpr (sizeof(TO) == 4) {
            *(float4*)&uo[(size_t)y * n + xm] =
                make_float4(out[0], out[1], out[2], out[3]);
        } else {
            ushort4 o;
            o.x = f2bf(out[0]); o.y = f2bf(out[1]);
            o.z = f2bf(out[2]); o.w = f2bf(out[3]);
            *(ushort4*)&uo[(size_t)y * n + xm] = o;
        }
        if (WANTMM) {
            mn = fminf(mn, fminf(fminf(out[0], out[1]), fminf(out[2], out[3])));
            mx = fmaxf(mx, fmaxf(fmaxf(out[0], out[1]), fmaxf(out[2], out[3])));
        }
    }
    if (WANTMM) {
#pragma unroll
        for (int off = 32; off > 0; off >>= 1) {
            mn = fminf(mn, __shfl_down(mn, off));
            mx = fmaxf(mx, __shfl_down(mx, off));
        }
        __shared__ float smn[4], smx[4];
        if (lane == 0) { smn[w] = mn; smx[w] = mx; }
        __syncthreads();
        if (t == 0) {
            mn = smn[0]; mx = smx[0];
            for (int wq = 1; wq < 4; ++wq) { mn = fminf(mn, smn[wq]); mx = fmaxf(mx, smx[wq]); }
            int bid = by * 16 + bx;
            partials[2 * bid] = mn;
            partials[2 * bid + 1] = mx;
        }
    }
}

__global__ __launch_bounds__(1024) void minmax_final_kernel(
    const float* __restrict__ partials, float* __restrict__ mm)
{
    float mn = 3.402823466e+38f, mx = -3.402823466e+38f;
    for (int i = threadIdx.x; i < 2048; i += 1024) {
        mn = fminf(mn, partials[2 * i]);
        mx = fmaxf(mx, partials[2 * i + 1]);
    }
#pragma unroll
    for (int off = 32; off > 0; off >>= 1) {
        mn = fminf(mn, __shfl_down(mn, off));
        mx = fmaxf(mx, __shfl_down(mx, off));
    }
    __shared__ float smn[16], smx[16];
    int lane = threadIdx.x & 63, wv = threadIdx.x >> 6;
    if (lane == 0) { smn[wv] = mn; smx[wv] = mx; }
    __syncthreads();
    if (threadIdx.x == 0) {
        mn = smn[0]; mx = smx[0];
        for (int w = 1; w < 16; ++w) { mn = fminf(mn, smn[w]); mx = fmaxf(mx, smx[w]); }
        mm[0] = mn;
        mm[1] = mx;
    }
}

__global__ __launch_bounds__(256) void normalize_kernel(
    float* __restrict__ u, const float* __restrict__ mm)
{
    size_t i = ((size_t)blockIdx.x * 256 + threadIdx.x) * 4;
    float mn = mm[0];
    float sc = 1.0f / (mm[1] - mm[0]);
    float4 v = *(float4*)&u[i];
    v.x = (v.x - mn) * sc;
    v.y = (v.y - mn) * sc;
    v.z = (v.z - mn) * sc;
    v.w = (v.w - mn) * sc;
    *(float4*)&u[i] = v;
}

extern "C" void kernel_launch(void* const* d_in, const int* in_sizes, int n_in,
                              void* d_out, int out_size, void* d_ws, size_t ws_size,
                              hipStream_t stream)
{
    const float* A  = (const float*)d_in[0];
    const float* u0 = (const float*)d_in[1];
    float* uout = (float*)d_out;
    char* ws = (char*)d_ws;

    size_t off = 0;
    auto alloc_f = [&](size_t nelem) { float* p = (float*)(ws + off); off += nelem * 4; return p; };
    float* r2 = alloc_f(1024ull * 1024);
    float* r3 = alloc_f(512ull * 512);
    float* r4 = alloc_f(256ull * 256);
    float* r5 = alloc_f(128ull * 128);
    float* r6 = alloc_f(64ull * 64);
    float* r7 = alloc_f(32ull * 32);
    float* e5 = alloc_f(512ull * 512);
    float* partials = alloc_f(4096);
    float* mm = alloc_f(2);
    off = (off + 15) & ~15ull;
    unsigned short* ubA = (unsigned short*)(ws + off); off += 4096ull * 4096 * 2;
    unsigned short* ubB = (unsigned short*)(ws + off); off += 4096ull * 4096 * 2;

    // it0: u0(f32) -> ubA ; it1: ubA -> ubB ; it2: ubB -> ubA ; it3: ubA -> uout(f32)
    for (int it = 0; it < 4; ++it) {
        if (it == 0) {
            smooth_restrict2_kernel<float><<<2048, 256, 0, stream>>>(u0, A, r2, r3);
        } else {
            const unsigned short* us = (it == 2) ? ubB : ubA;
            smooth_restrict2_kernel<unsigned short><<<2048, 256, 0, stream>>>(us, A, r2, r3);
        }
        multirestrict_kernel<<<dim3(16, 16), 256, 0, stream>>>(r3, r4, r5, r6, r7);
        coarse_up_kernel<<<dim3(16, 16), 256, 0, stream>>>(r7, r6, r5, r4, r3, A, e5);
        if (it == 0) {
            final_fused_kernel<float, unsigned short, false><<<2048, 256, 0, stream>>>(
                u0, e5, r2, A, ubA, partials);
        } else if (it == 1) {
            final_fused_kernel<unsigned short, unsigned short, false><<<2048, 256, 0, stream>>>(
                ubA, e5, r2, A, ubB, partials);
        } else if (it == 2) {
            final_fused_kernel<unsigned short, unsigned short, false><<<2048, 256, 0, stream>>>(
                ubB, e5, r2, A, ubA, partials);
        } else {
            final_fused_kernel<unsigned short, float, true><<<2048, 256, 0, stream>>>(
                ubA, e5, r2, A, uout, partials);
        }
    }
    minmax_final_kernel<<<1, 1024, 0, stream>>>(partials, mm);
    normalize_kernel<<<16384, 256, 0, stream>>>(uout, mm);
}

// Round 13
// 204.985 us; speedup vs baseline: 1.4677x; 1.0563x over previous
//
#include <hip/hip_runtime.h>

#define N 4096

__device__ __forceinline__ float bf2f(unsigned short h)
{
    unsigned int u = ((unsigned int)h) << 16;
    return __uint_as_float(u);
}
__device__ __forceinline__ unsigned short f2bf(float f)
{
    unsigned int x = __float_as_uint(f);
    unsigned int r = (x + 0x7FFFu + ((x >> 16) & 1u)) >> 16;  // round-nearest-even
    return (unsigned short)r;
}

__device__ __forceinline__ void load_A(const float* __restrict__ Ag,
                                       float Ac[3][3], float& inv)
{
#pragma unroll
    for (int i = 0; i < 9; ++i) Ac[i / 3][i % 3] = Ag[i];
    inv = 1.0f / Ac[1][1];
    Ac[1][1] = 0.f;
}

__device__ __forceinline__ void make_w44(const float Ac[3][3], float wt[4][4])
{
#pragma unroll
    for (int a = 0; a < 4; ++a)
#pragma unroll
        for (int b = 0; b < 4; ++b) wt[a][b] = 0.f;
#pragma unroll
    for (int r = 0; r < 2; ++r)
#pragma unroll
        for (int c = 0; c < 2; ++c)
#pragma unroll
            for (int i = 0; i < 3; ++i)
#pragma unroll
                for (int j = 0; j < 3; ++j) wt[r + i][c + j] += Ac[i][j];
}

// Branch-free u_bc row segment (f32 or bf16 storage; math in f32).
template <typename TI>
__device__ __forceinline__ void load_row6T(const TI* __restrict__ u,
                                           int gy, int xm, int colL, int colR,
                                           bool cornL, bool cornR, bool yedge,
                                           float v[6])
{
    int cy = min(max(gy, 0), N - 1);
    const TI* rowp = &u[(size_t)cy * N];
    float L, R;
    if constexpr (sizeof(TI) == 4) {
        float4 m = *(const float4*)&rowp[xm];
        v[1] = m.x; v[2] = m.y; v[3] = m.z; v[4] = m.w;
        L = rowp[colL];
        R = rowp[colR];
    } else {
        ushort4 m = *(const ushort4*)&rowp[xm];
        v[1] = bf2f(m.x); v[2] = bf2f(m.y); v[3] = bf2f(m.z); v[4] = bf2f(m.w);
        L = bf2f(rowp[colL]);
        R = bf2f(rowp[colR]);
    }
    if (yedge) {
        bool oob = (gy < 0) | (gy >= N);
        if (oob & cornL) L = 0.f;
        if (oob & cornR) R = 0.f;
    }
    v[0] = L; v[5] = R;
}

// XCD-aware bijective swizzle for 2048-block 1D grids (2048 % 8 == 0).
__device__ __forceinline__ void swz2048(int bid, int& bx, int& by)
{
    int reg = (bid & 7) * 256 + (bid >> 3);
    bx = reg & 15;
    by = reg >> 4;
}

// ---- fused smooth(bc(u)) + restrict + restrict -> r2(bf16, 1024^2) + r3(f32, 512^2) ----
template <typename TI>
__global__ __launch_bounds__(256) void smooth_restrict2_kernel(
    const TI* __restrict__ u, const float* __restrict__ Ag,
    unsigned short* __restrict__ r2, float* __restrict__ r3)
{
    int t = threadIdx.x, lane = t & 63, w = t >> 6;
    int bx, by;
    swz2048(blockIdx.x, bx, by);
    int x0 = 256 * bx;
    int Y0 = 16 * by + 4 * w;
    int gy0 = 2 * Y0 - 1;
    bool yedge = (gy0 < 0) | (gy0 + 9 >= N);
    float Ac[3][3], inv;
    load_A(Ag, Ac, inv);
    float wt[4][4];
    make_w44(Ac, wt);

    int xm = x0 + 4 * lane;
    int colL = max(xm - 1, 0), colR = min(xm + 4, N - 1);
    bool cornL = (xm - 1 < 0), cornR = (xm + 4 >= N);
    float v[10][6];
#pragma unroll
    for (int rr = 0; rr < 10; ++rr)
        load_row6T<TI>(u, gy0 + rr, xm, colL, colR, cornL, cornR, yedge, v[rr]);

    float o0[4], o1[4];
#pragma unroll
    for (int q = 0; q < 4; ++q) {
        float a0 = 0.f, a1 = 0.f;
#pragma unroll
        for (int a = 0; a < 4; ++a) {
            const float* vv = v[2 * q + a];
#pragma unroll
            for (int b = 0; b < 4; ++b) {
                a0 += wt[a][b] * vv[b];
                a1 += wt[a][b] * vv[b + 2];
            }
        }
        o0[q] = 0.25f * a0;
        o1[q] = 0.25f * a1;
    }
    int Y2 = Y0 >> 1, X2 = 64 * bx + lane;   // Y2 even
    float val0 = 0.25f * (o0[0] + o1[0] + o0[1] + o1[1]);
    float val1 = 0.25f * (o0[2] + o1[2] + o0[3] + o1[3]);
    r2[(size_t)Y2 * 1024 + X2] = f2bf(val0);
    r2[(size_t)(Y2 + 1) * 1024 + X2] = f2bf(val1);
    float s0 = val0 + val1;
    float s1 = __shfl_xor(s0, 1);
    if (!(lane & 1))
        r3[(size_t)(Y2 >> 1) * 512 + (X2 >> 1)] = 0.25f * (s0 + s1);
}

// ---- restriction tree: r3 -> r4..r7 (grid 16x16) ----
__global__ __launch_bounds__(256) void multirestrict_kernel(
    const float* __restrict__ r3, float* __restrict__ r4, float* __restrict__ r5,
    float* __restrict__ r6, float* __restrict__ r7)
{
    int BX = blockIdx.x, BY = blockIdx.y;
    __shared__ float s4[16][17];
    __shared__ float s5[8][9];
    __shared__ float s6[4][5];
    int t = threadIdx.x;
    {
        int y = t >> 4, x = t & 15;
        const float* b0 = &r3[(size_t)(32 * BY + 2 * y) * 512 + 32 * BX + 2 * x];
        float2 a = *(const float2*)b0;
        float2 b = *(const float2*)(b0 + 512);
        float vv = 0.25f * (a.x + a.y + b.x + b.y);
        r4[(size_t)(16 * BY + y) * 256 + 16 * BX + x] = vv;
        s4[y][x] = vv;
    }
    __syncthreads();
    if (t < 64) {
        int y = t >> 3, x = t & 7;
        float vv = 0.25f * (s4[2 * y][2 * x] + s4[2 * y][2 * x + 1] +
                            s4[2 * y + 1][2 * x] + s4[2 * y + 1][2 * x + 1]);
        r5[(size_t)(8 * BY + y) * 128 + 8 * BX + x] = vv;
        s5[y][x] = vv;
    }
    __syncthreads();
    if (t < 16) {
        int y = t >> 2, x = t & 3;
        float vv = 0.25f * (s5[2 * y][2 * x] + s5[2 * y][2 * x + 1] +
                            s5[2 * y + 1][2 * x] + s5[2 * y + 1][2 * x + 1]);
        r6[(size_t)(4 * BY + y) * 64 + 4 * BX + x] = vv;
        s6[y][x] = vv;
    }
    __syncthreads();
    if (t < 4) {
        int y = t >> 1, x = t & 1;
        float vv = 0.25f * (s6[2 * y][2 * x] + s6[2 * y][2 * x + 1] +
                            s6[2 * y + 1][2 * x] + s6[2 * y + 1][2 * x + 1]);
        r7[(size_t)(2 * BY + y) * 32 + 2 * BX + x] = vv;
    }
}

// ---- fused coarse up-chain: r7..r3 -> e@512 ----
__global__ __launch_bounds__(256) void coarse_up_kernel(
    const float* __restrict__ r7, const float* __restrict__ r6,
    const float* __restrict__ r5, const float* __restrict__ r4,
    const float* __restrict__ r3, const float* __restrict__ Ag,
    float* __restrict__ e512)
{
    int bx = blockIdx.x, by = blockIdx.y;
    int t = threadIdx.x;
    __shared__ float s7[32][33];
    __shared__ float s64[64][65];
    __shared__ float s128[11][12];
    __shared__ float s256[18][19];
    float Ac[3][3], inv;
    load_A(Ag, Ac, inv);
    for (int i = t; i < 1024; i += 256) s7[i >> 5][i & 31] = r7[i] * inv;
    __syncthreads();
    for (int i = t; i < 4096; i += 256) {
        int y = i >> 6, x = i & 63;
        float ctr = s7[y >> 1][x >> 1];
        float sm = 0.f;
#pragma unroll
        for (int dy = -1; dy <= 1; ++dy)
#pragma unroll
            for (int dx = -1; dx <= 1; ++dx) {
                if (dy == 0 && dx == 0) continue;
                int yy = y + dy, xx = x + dx;
                float pe = 0.f;
                if (yy >= 0 && yy < 64 && xx >= 0 && xx < 64) pe = s7[yy >> 1][xx >> 1];
                sm += Ac[dy + 1][dx + 1] * pe;
            }
        s64[y][x] = ctr - sm * inv + r6[i] * inv;
    }
    __syncthreads();
    int R1 = 8 * by - 2, C1 = 8 * bx - 2;
    if (t < 121) {
        int pr = t / 11, pc = t % 11;
        int gy = R1 + pr, gx = C1 + pc;
        if (gy >= 0 && gy < 128 && gx >= 0 && gx < 128) {
            float ctr = s64[gy >> 1][gx >> 1];
            float sm = 0.f;
#pragma unroll
            for (int dy = -1; dy <= 1; ++dy)
#pragma unroll
                for (int dx = -1; dx <= 1; ++dx) {
                    if (dy == 0 && dx == 0) continue;
                    int yy = gy + dy, xx = gx + dx;
                    float pe = 0.f;
                    if (yy >= 0 && yy < 128 && xx >= 0 && xx < 128) pe = s64[yy >> 1][xx >> 1];
                    sm += Ac[dy + 1][dx + 1] * pe;
                }
            s128[pr][pc] = ctr - sm * inv + r5[(size_t)gy * 128 + gx] * inv;
        }
    }
    __syncthreads();
    int R2l = 16 * by - 1, C2l = 16 * bx - 1;
    for (int i = t; i < 324; i += 256) {
        int pr = i / 18, pc = i % 18;
        int gy = R2l + pr, gx = C2l + pc;
        if (gy >= 0 && gy < 256 && gx >= 0 && gx < 256) {
            float ctr = s128[(gy >> 1) - R1][(gx >> 1) - C1];
            float sm = 0.f;
#pragma unroll
            for (int dy = -1; dy <= 1; ++dy)
#pragma unroll
                for (int dx = -1; dx <= 1; ++dx) {
                    if (dy == 0 && dx == 0) continue;
                    int yy = gy + dy, xx = gx + dx;
                    float pe = 0.f;
                    if (yy >= 0 && yy < 256 && xx >= 0 && xx < 256)
                        pe = s128[(yy >> 1) - R1][(xx >> 1) - C1];
                    sm += Ac[dy + 1][dx + 1] * pe;
                }
            s256[pr][pc] = ctr - sm * inv + r4[(size_t)gy * 256 + gx] * inv;
        }
    }
    __syncthreads();
#pragma unroll
    for (int k = 0; k < 4; ++k) {
        int idx = t + 256 * k;
        int y = 32 * by + (idx >> 5), x = 32 * bx + (idx & 31);
        float ctr = s256[(y >> 1) - R2l][(x >> 1) - C2l];
        float sm = 0.f;
#pragma unroll
        for (int dy = -1; dy <= 1; ++dy)
#pragma unroll
            for (int dx = -1; dx <= 1; ++dx) {
                if (dy == 0 && dx == 0) continue;
                int yy = y + dy, xx = x + dx;
                float pe = 0.f;
                if (yy >= 0 && yy < 512 && xx >= 0 && xx < 512)
                    pe = s256[(yy >> 1) - R2l][(xx >> 1) - C2l];
                sm += Ac[dy + 1][dx + 1] * pe;
            }
        e512[(size_t)y * 512 + x] = ctr - sm * inv + r3[(size_t)y * 512 + x] * inv;
    }
}

// ---- fused: e512 -> e1024 (LDS) -> e2048 (regs, r1 recomputed) -> u update ----
// TI/TO: float or ushort(bf16) storage for u_in / u_out. r2 stored bf16.
template <typename TI, typename TO, bool WANTMM>
__global__ __launch_bounds__(256) void final_fused_kernel(
    const TI* __restrict__ u, const float* __restrict__ e512,
    const unsigned short* __restrict__ r2, const float* __restrict__ Ag,
    TO* __restrict__ uo, float* __restrict__ partials)
{
    const int n = N;
    int t = threadIdx.x, lane = t & 63, w = t >> 6;
    int bx, by;
    swz2048(blockIdx.x, bx, by);
    int x0 = 256 * bx, y0 = 32 * by;
    __shared__ float s512v[6][36];
    __shared__ float s1024[10][68];
    float Ac[3][3], inv;
    load_A(Ag, Ac, inv);
    float wt[4][4];
    make_w44(Ac, wt);

    int yb = y0 + 8 * w;
    int gy0 = yb - 1;
    bool yedge = (gy0 < 0) | (gy0 + 9 >= n);
    int xm = x0 + 4 * lane;
    int colL = max(xm - 1, 0), colR = min(xm + 4, n - 1);
    bool cornL = (xm - 1 < 0), cornR = (xm + 4 >= n);
    float v[10][6];
#pragma unroll
    for (int rr = 0; rr < 10; ++rr)
        load_row6T<TI>(u, gy0 + rr, xm, colL, colR, cornL, cornR, yedge, v[rr]);

    int S5r = 4 * by - 1, S5c = 32 * bx - 1;
    if (t < 216) {
        int pr = t / 36, pc = t - (t / 36) * 36;
        int gy = S5r + pr, gx = S5c + pc;
        float vv = 0.f;
        if (pc < 34 && gy >= 0 && gy < 512 && gx >= 0 && gx < 512)
            vv = e512[(size_t)gy * 512 + gx];
        s512v[pr][pc] = vv;
    }
    __syncthreads();
    int R10 = 8 * by - 1, C10 = 64 * bx - 1;
    for (int i = t; i < 680; i += 256) {
        int pr = i / 68, pc = i - (i / 68) * 68;
        if (pc < 66) {
            int gy = R10 + pr, gx = C10 + pc;
            float val = 0.f;
            if (gy >= 0 && gy < 1024 && gx >= 0 && gx < 1024) {
                float ctr = s512v[(gy >> 1) - S5r][(gx >> 1) - S5c];
                float sm = 0.f;
#pragma unroll
                for (int dy = -1; dy <= 1; ++dy)
#pragma unroll
                    for (int dx = -1; dx <= 1; ++dx) {
                        if (dy == 0 && dx == 0) continue;
                        sm += Ac[dy + 1][dx + 1] *
                              s512v[((gy + dy) >> 1) - S5r][((gx + dx) >> 1) - S5c];
                    }
                val = ctr - sm * inv + bf2f(r2[(size_t)gy * 1024 + gx]) * inv;
            }
            s1024[pr][pc] = val;
        }
    }
    __syncthreads();
    float e2[4][2];
    int EY0 = 16 * by + 4 * w, EX0 = 128 * bx + 2 * lane;
#pragma unroll
    for (int a = 0; a < 4; ++a) {
        int gy = EY0 + a;
        float a0 = 0.f, a1 = 0.f;
#pragma unroll
        for (int i = 0; i < 4; ++i) {
            const float* vv = v[2 * a + i];
#pragma unroll
            for (int j = 0; j < 4; ++j) {
                a0 += wt[i][j] * vv[j];
                a1 += wt[i][j] * vv[j + 2];
            }
        }
        float r1v[2] = {0.25f * a0, 0.25f * a1};
#pragma unroll
        for (int b = 0; b < 2; ++b) {
            int gx = EX0 + b;
            float ctr = s1024[(gy >> 1) - R10][(gx >> 1) - C10];
            float sm = 0.f;
#pragma unroll
            for (int dy = -1; dy <= 1; ++dy)
#pragma unroll
                for (int dx = -1; dx <= 1; ++dx) {
                    if (dy == 0 && dx == 0) continue;
                    sm += Ac[dy + 1][dx + 1] *
                          s1024[((gy + dy) >> 1) - R10][((gx + dx) >> 1) - C10];
                }
            e2[a][b] = ctr - sm * inv + r1v[b] * inv;
        }
    }
    float mn = 3.402823466e+38f, mx = -3.402823466e+38f;
#pragma unroll
    for (int r = 0; r < 8; ++r) {
        int y = yb + r;
        const float* va = v[r];
        const float* vb = v[r + 1];
        const float* vc = v[r + 2];
        float out[4];
#pragma unroll
        for (int c = 0; c < 4; ++c) {
            float sm = Ac[0][0] * va[c] + Ac[0][1] * va[c + 1] + Ac[0][2] * va[c + 2]
                     + Ac[1][0] * vb[c]                        + Ac[1][2] * vb[c + 2]
                     + Ac[2][0] * vc[c] + Ac[2][1] * vc[c + 1] + Ac[2][2] * vc[c + 2];
            out[c] = vb[c + 1] - e2[r >> 1][c >> 1] - sm * inv;
        }
        if constexpr (sizeof(TO) == 4) {
            *(float4*)&uo[(size_t)y * n + xm] =
                make_float4(out[0], out[1], out[2], out[3]);
        } else {
            ushort4 o;
            o.x = f2bf(out[0]); o.y = f2bf(out[1]);
            o.z = f2bf(out[2]); o.w = f2bf(out[3]);
            *(ushort4*)&uo[(size_t)y * n + xm] = o;
        }
        if (WANTMM) {
            mn = fminf(mn, fminf(fminf(out[0], out[1]), fminf(out[2], out[3])));
            mx = fmaxf(mx, fmaxf(fmaxf(out[0], out[1]), fmaxf(out[2], out[3])));
        }
    }
    if (WANTMM) {
#pragma unroll
        for (int off = 32; off > 0; off >>= 1) {
            mn = fminf(mn, __shfl_down(mn, off));
            mx = fmaxf(mx, __shfl_down(mx, off));
        }
        __shared__ float smn[4], smx[4];
        if (lane == 0) { smn[w] = mn; smx[w] = mx; }
        __syncthreads();
        if (t == 0) {
            mn = smn[0]; mx = smx[0];
            for (int wq = 1; wq < 4; ++wq) { mn = fminf(mn, smn[wq]); mx = fmaxf(mx, smx[wq]); }
            int bid = by * 16 + bx;
            partials[2 * bid] = mn;
            partials[2 * bid + 1] = mx;
        }
    }
}

__global__ __launch_bounds__(1024) void minmax_final_kernel(
    const float* __restrict__ partials, float* __restrict__ mm)
{
    float mn = 3.402823466e+38f, mx = -3.402823466e+38f;
    for (int i = threadIdx.x; i < 2048; i += 1024) {
        mn = fminf(mn, partials[2 * i]);
        mx = fmaxf(mx, partials[2 * i + 1]);
    }
#pragma unroll
    for (int off = 32; off > 0; off >>= 1) {
        mn = fminf(mn, __shfl_down(mn, off));
        mx = fmaxf(mx, __shfl_down(mx, off));
    }
    __shared__ float smn[16], smx[16];
    int lane = threadIdx.x & 63, wv = threadIdx.x >> 6;
    if (lane == 0) { smn[wv] = mn; smx[wv] = mx; }
    __syncthreads();
    if (threadIdx.x == 0) {
        mn = smn[0]; mx = smx[0];
        for (int w = 1; w < 16; ++w) { mn = fminf(mn, smn[w]); mx = fmaxf(mx, smx[w]); }
        mm[0] = mn;
        mm[1] = mx;
    }
}

// normalize: read bf16 u, write f32 output
__global__ __launch_bounds__(256) void normalize_kernel(
    const unsigned short* __restrict__ uin, float* __restrict__ uout,
    const float* __restrict__ mm)
{
    size_t i = ((size_t)blockIdx.x * 256 + threadIdx.x) * 4;
    float mn = mm[0];
    float sc = 1.0f / (mm[1] - mm[0]);
    ushort4 h = *(const ushort4*)&uin[i];
    float4 v;
    v.x = (bf2f(h.x) - mn) * sc;
    v.y = (bf2f(h.y) - mn) * sc;
    v.z = (bf2f(h.z) - mn) * sc;
    v.w = (bf2f(h.w) - mn) * sc;
    *(float4*)&uout[i] = v;
}

extern "C" void kernel_launch(void* const* d_in, const int* in_sizes, int n_in,
                              void* d_out, int out_size, void* d_ws, size_t ws_size,
                              hipStream_t stream)
{
    const float* A  = (const float*)d_in[0];
    const float* u0 = (const float*)d_in[1];
    float* uout = (float*)d_out;
    char* ws = (char*)d_ws;

    size_t off = 0;
    auto alloc_f = [&](size_t nelem) { float* p = (float*)(ws + off); off += nelem * 4; return p; };
    float* r3 = alloc_f(512ull * 512);
    float* r4 = alloc_f(256ull * 256);
    float* r5 = alloc_f(128ull * 128);
    float* r6 = alloc_f(64ull * 64);
    float* r7 = alloc_f(32ull * 32);
    float* e5 = alloc_f(512ull * 512);
    float* partials = alloc_f(4096);
    float* mm = alloc_f(2);
    off = (off + 15) & ~15ull;
    unsigned short* r2 = (unsigned short*)(ws + off); off += 1024ull * 1024 * 2;
    off = (off + 15) & ~15ull;
    unsigned short* ubA = (unsigned short*)(ws + off); off += 4096ull * 4096 * 2;
    unsigned short* ubB = (unsigned short*)(ws + off); off += 4096ull * 4096 * 2;

    // it0: u0(f32) -> ubA ; it1: ubA -> ubB ; it2: ubB -> ubA ; it3: ubA -> ubB(bf16)
    for (int it = 0; it < 4; ++it) {
        if (it == 0) {
            smooth_restrict2_kernel<float><<<2048, 256, 0, stream>>>(u0, A, r2, r3);
        } else {
            const unsigned short* us = (it == 2) ? ubB : ubA;
            smooth_restrict2_kernel<unsigned short><<<2048, 256, 0, stream>>>(us, A, r2, r3);
        }
        multirestrict_kernel<<<dim3(16, 16), 256, 0, stream>>>(r3, r4, r5, r6, r7);
        coarse_up_kernel<<<dim3(16, 16), 256, 0, stream>>>(r7, r6, r5, r4, r3, A, e5);
        if (it == 0) {
            final_fused_kernel<float, unsigned short, false><<<2048, 256, 0, stream>>>(
                u0, e5, r2, A, ubA, partials);
        } else if (it == 1) {
            final_fused_kernel<unsigned short, unsigned short, false><<<2048, 256, 0, stream>>>(
                ubA, e5, r2, A, ubB, partials);
        } else if (it == 2) {
            final_fused_kernel<unsigned short, unsigned short, false><<<2048, 256, 0, stream>>>(
                ubB, e5, r2, A, ubA, partials);
        } else {
            final_fused_kernel<unsigned short, unsigned short, true><<<2048, 256, 0, stream>>>(
                ubA, e5, r2, A, ubB, partials);
        }
    }
    minmax_final_kernel<<<1, 1024, 0, stream>>>(partials, mm);
    normalize_kernel<<<16384, 256, 0, stream>>>(ubB, uout, mm);
}

// Round 14
// 175.430 us; speedup vs baseline: 1.7150x; 1.1685x over previous
//
#include <hip/hip_runtime.h>

#define N 4096

__device__ __forceinline__ float bf2f(unsigned short h)
{
    unsigned int u = ((unsigned int)h) << 16;
    return __uint_as_float(u);
}
__device__ __forceinline__ unsigned short f2bf(float f)
{
    unsigned int x = __float_as_uint(f);
    unsigned int r = (x + 0x7FFFu + ((x >> 16) & 1u)) >> 16;  // round-nearest-even
    return (unsigned short)r;
}

// floor((i)/2) valid for i >= -1024 (branch-free, no reliance on negative >>)
__device__ __forceinline__ int cr(int i) { return ((i + 1024) >> 1) - 512; }

__device__ __forceinline__ void load_A(const float* __restrict__ Ag,
                                       float Ac[3][3], float& inv)
{
#pragma unroll
    for (int i = 0; i < 9; ++i) Ac[i / 3][i % 3] = Ag[i];
    inv = 1.0f / Ac[1][1];
    Ac[1][1] = 0.f;
}

__device__ __forceinline__ void make_w44(const float Ac[3][3], float wt[4][4])
{
#pragma unroll
    for (int a = 0; a < 4; ++a)
#pragma unroll
        for (int b = 0; b < 4; ++b) wt[a][b] = 0.f;
#pragma unroll
    for (int r = 0; r < 2; ++r)
#pragma unroll
        for (int c = 0; c < 2; ++c)
#pragma unroll
            for (int i = 0; i < 3; ++i)
#pragma unroll
                for (int j = 0; j < 3; ++j) wt[r + i][c + j] += Ac[i][j];
}

// Branch-free u_bc row segment (f32 or bf16 storage; math in f32).
template <typename TI>
__device__ __forceinline__ void load_row6T(const TI* __restrict__ u,
                                           int gy, int xm, int colL, int colR,
                                           bool cornL, bool cornR, bool yedge,
                                           float v[6])
{
    int cy = min(max(gy, 0), N - 1);
    const TI* rowp = &u[(size_t)cy * N];
    float L, R;
    if constexpr (sizeof(TI) == 4) {
        float4 m = *(const float4*)&rowp[xm];
        v[1] = m.x; v[2] = m.y; v[3] = m.z; v[4] = m.w;
        L = rowp[colL];
        R = rowp[colR];
    } else {
        ushort4 m = *(const ushort4*)&rowp[xm];
        v[1] = bf2f(m.x); v[2] = bf2f(m.y); v[3] = bf2f(m.z); v[4] = bf2f(m.w);
        L = bf2f(rowp[colL]);
        R = bf2f(rowp[colR]);
    }
    if (yedge) {
        bool oob = (gy < 0) | (gy >= N);
        if (oob & cornL) L = 0.f;
        if (oob & cornR) R = 0.f;
    }
    v[0] = L; v[5] = R;
}

// XCD-aware bijective swizzle for 2048-block 1D grids (2048 % 8 == 0).
__device__ __forceinline__ void swz2048(int bid, int& bx, int& by)
{
    int reg = (bid & 7) * 256 + (bid >> 3);
    bx = reg & 15;
    by = reg >> 4;
}

// ---- fused smooth(bc(u)) + restrict + restrict -> r2(bf16, 1024^2) + r3(f32, 512^2) ----
template <typename TI>
__global__ __launch_bounds__(256) void smooth_restrict2_kernel(
    const TI* __restrict__ u, const float* __restrict__ Ag,
    unsigned short* __restrict__ r2, float* __restrict__ r3)
{
    int t = threadIdx.x, lane = t & 63, w = t >> 6;
    int bx, by;
    swz2048(blockIdx.x, bx, by);
    int x0 = 256 * bx;
    int Y0 = 16 * by + 4 * w;
    int gy0 = 2 * Y0 - 1;
    bool yedge = (gy0 < 0) | (gy0 + 9 >= N);
    float Ac[3][3], inv;
    load_A(Ag, Ac, inv);
    float wt[4][4];
    make_w44(Ac, wt);

    int xm = x0 + 4 * lane;
    int colL = max(xm - 1, 0), colR = min(xm + 4, N - 1);
    bool cornL = (xm - 1 < 0), cornR = (xm + 4 >= N);
    float v[10][6];
#pragma unroll
    for (int rr = 0; rr < 10; ++rr)
        load_row6T<TI>(u, gy0 + rr, xm, colL, colR, cornL, cornR, yedge, v[rr]);

    float o0[4], o1[4];
#pragma unroll
    for (int q = 0; q < 4; ++q) {
        float a0 = 0.f, a1 = 0.f;
#pragma unroll
        for (int a = 0; a < 4; ++a) {
            const float* vv = v[2 * q + a];
#pragma unroll
            for (int b = 0; b < 4; ++b) {
                a0 += wt[a][b] * vv[b];
                a1 += wt[a][b] * vv[b + 2];
            }
        }
        o0[q] = 0.25f * a0;
        o1[q] = 0.25f * a1;
    }
    int Y2 = Y0 >> 1, X2 = 64 * bx + lane;   // Y2 even
    float val0 = 0.25f * (o0[0] + o1[0] + o0[1] + o1[1]);
    float val1 = 0.25f * (o0[2] + o1[2] + o0[3] + o1[3]);
    r2[(size_t)Y2 * 1024 + X2] = f2bf(val0);
    r2[(size_t)(Y2 + 1) * 1024 + X2] = f2bf(val1);
    float s0 = val0 + val1;
    float s1 = __shfl_xor(s0, 1);
    if (!(lane & 1))
        r3[(size_t)(Y2 >> 1) * 512 + (X2 >> 1)] = 0.25f * (s0 + s1);
}

// ---- restriction tree: r3 -> r4..r7 (grid 16x16) ----
__global__ __launch_bounds__(256) void multirestrict_kernel(
    const float* __restrict__ r3, float* __restrict__ r4, float* __restrict__ r5,
    float* __restrict__ r6, float* __restrict__ r7)
{
    int BX = blockIdx.x, BY = blockIdx.y;
    __shared__ float s4[16][17];
    __shared__ float s5[8][9];
    __shared__ float s6[4][5];
    int t = threadIdx.x;
    {
        int y = t >> 4, x = t & 15;
        const float* b0 = &r3[(size_t)(32 * BY + 2 * y) * 512 + 32 * BX + 2 * x];
        float2 a = *(const float2*)b0;
        float2 b = *(const float2*)(b0 + 512);
        float vv = 0.25f * (a.x + a.y + b.x + b.y);
        r4[(size_t)(16 * BY + y) * 256 + 16 * BX + x] = vv;
        s4[y][x] = vv;
    }
    __syncthreads();
    if (t < 64) {
        int y = t >> 3, x = t & 7;
        float vv = 0.25f * (s4[2 * y][2 * x] + s4[2 * y][2 * x + 1] +
                            s4[2 * y + 1][2 * x] + s4[2 * y + 1][2 * x + 1]);
        r5[(size_t)(8 * BY + y) * 128 + 8 * BX + x] = vv;
        s5[y][x] = vv;
    }
    __syncthreads();
    if (t < 16) {
        int y = t >> 2, x = t & 3;
        float vv = 0.25f * (s5[2 * y][2 * x] + s5[2 * y][2 * x + 1] +
                            s5[2 * y + 1][2 * x] + s5[2 * y + 1][2 * x + 1]);
        r6[(size_t)(4 * BY + y) * 64 + 4 * BX + x] = vv;
        s6[y][x] = vv;
    }
    __syncthreads();
    if (t < 4) {
        int y = t >> 1, x = t & 1;
        float vv = 0.25f * (s6[2 * y][2 * x] + s6[2 * y][2 * x + 1] +
                            s6[2 * y + 1][2 * x] + s6[2 * y + 1][2 * x + 1]);
        r7[(size_t)(2 * BY + y) * 32 + 2 * BX + x] = vv;
    }
}

// ---- fused: full coarse e-chain (r7..r3 patches) -> e1024 -> e2048(regs) -> u update ----
// TI/TO: float or ushort(bf16) storage for u_in / u_out. r2 stored bf16.
template <typename TI, typename TO, bool WANTMM>
__global__ __launch_bounds__(256) void final_fused_kernel(
    const TI* __restrict__ u,
    const float* __restrict__ r7, const float* __restrict__ r6,
    const float* __restrict__ r5, const float* __restrict__ r4,
    const float* __restrict__ r3, const unsigned short* __restrict__ r2,
    const float* __restrict__ Ag, TO* __restrict__ uo,
    float* __restrict__ partials)
{
    const int n = N;
    int t = threadIdx.x, lane = t & 63, w = t >> 6;
    int bx, by;
    swz2048(blockIdx.x, bx, by);
    int x0 = 256 * bx, y0 = 32 * by;
    __shared__ float s32p[3][4];     // e32 = r7/diag, zero-padded halo
    __shared__ float s64p[3][6];
    __shared__ float s128p[3][10];
    __shared__ float s256p[4][18];
    __shared__ float s512v[6][36];
    __shared__ float s1024[10][68];
    float Ac[3][3], inv;
    load_A(Ag, Ac, inv);
    float wt[4][4];
    make_w44(Ac, wt);

    // issue u row loads first (MLP hides HBM latency under the e-chain phases)
    int yb = y0 + 8 * w;
    int gyu = yb - 1;
    bool yedge = (gyu < 0) | (gyu + 9 >= n);
    int xm = x0 + 4 * lane;
    int colL = max(xm - 1, 0), colR = min(xm + 4, n - 1);
    bool cornL = (xm - 1 < 0), cornR = (xm + 4 >= n);
    float v[10][6];
#pragma unroll
    for (int rr = 0; rr < 10; ++rr)
        load_row6T<TI>(u, gyu + rr, xm, colL, colR, cornL, cornR, yedge, v[rr]);

    // ---- level 32: r7/diag patch [3][4] ----
    int R32 = (by >> 2) - 1, C32 = 2 * bx - 1;
    if (t < 12) {
        int pr = t >> 2, pc = t & 3;
        int gy = R32 + pr, gx = C32 + pc;
        s32p[pr][pc] = (gy >= 0 && gy < 32 && gx >= 0 && gx < 32)
                           ? r7[(size_t)gy * 32 + gx] * inv : 0.f;
    }
    __syncthreads();
    // ---- level 64 patch [3][6] ----
    int R64 = (by >> 1) - 1, C64 = 4 * bx - 1;
    if (t < 18) {
        int pr = t / 6, pc = t - (t / 6) * 6;
        int gy = R64 + pr, gx = C64 + pc;
        float val = 0.f;
        if (gy >= 0 && gy < 64 && gx >= 0 && gx < 64) {
            float ctr = s32p[cr(gy) - R32][cr(gx) - C32];
            float sm = 0.f;
#pragma unroll
            for (int dy = -1; dy <= 1; ++dy)
#pragma unroll
                for (int dx = -1; dx <= 1; ++dx) {
                    if (dy == 0 && dx == 0) continue;
                    sm += Ac[dy + 1][dx + 1] * s32p[cr(gy + dy) - R32][cr(gx + dx) - C32];
                }
            val = ctr - sm * inv + r6[(size_t)gy * 64 + gx] * inv;
        }
        s64p[pr][pc] = val;
    }
    __syncthreads();
    // ---- level 128 patch [3][10] ----
    int R128 = by - 1, C128 = 8 * bx - 1;
    if (t < 30) {
        int pr = t / 10, pc = t - (t / 10) * 10;
        int gy = R128 + pr, gx = C128 + pc;
        float val = 0.f;
        if (gy >= 0 && gy < 128 && gx >= 0 && gx < 128) {
            float ctr = s64p[cr(gy) - R64][cr(gx) - C64];
            float sm = 0.f;
#pragma unroll
            for (int dy = -1; dy <= 1; ++dy)
#pragma unroll
                for (int dx = -1; dx <= 1; ++dx) {
                    if (dy == 0 && dx == 0) continue;
                    sm += Ac[dy + 1][dx + 1] * s64p[cr(gy + dy) - R64][cr(gx + dx) - C64];
                }
            val = ctr - sm * inv + r5[(size_t)gy * 128 + gx] * inv;
        }
        s128p[pr][pc] = val;
    }
    __syncthreads();
    // ---- level 256 patch [4][18] ----
    int R256 = 2 * by - 1, C256 = 16 * bx - 1;
    if (t < 72) {
        int pr = t / 18, pc = t - (t / 18) * 18;
        int gy = R256 + pr, gx = C256 + pc;
        float val = 0.f;
        if (gy >= 0 && gy < 256 && gx >= 0 && gx < 256) {
            float ctr = s128p[cr(gy) - R128][cr(gx) - C128];
            float sm = 0.f;
#pragma unroll
            for (int dy = -1; dy <= 1; ++dy)
#pragma unroll
                for (int dx = -1; dx <= 1; ++dx) {
                    if (dy == 0 && dx == 0) continue;
                    sm += Ac[dy + 1][dx + 1] * s128p[cr(gy + dy) - R128][cr(gx + dx) - C128];
                }
            val = ctr - sm * inv + r4[(size_t)gy * 256 + gx] * inv;
        }
        s256p[pr][pc] = val;
    }
    __syncthreads();
    // ---- level 512 patch [6][36] (34 used) ----
    int S5r = 4 * by - 1, S5c = 32 * bx - 1;
    if (t < 216) {
        int pr = t / 36, pc = t - (t / 36) * 36;
        int gy = S5r + pr, gx = S5c + pc;
        float val = 0.f;
        if (pc < 34 && gy >= 0 && gy < 512 && gx >= 0 && gx < 512) {
            float ctr = s256p[cr(gy) - R256][cr(gx) - C256];
            float sm = 0.f;
#pragma unroll
            for (int dy = -1; dy <= 1; ++dy)
#pragma unroll
                for (int dx = -1; dx <= 1; ++dx) {
                    if (dy == 0 && dx == 0) continue;
                    sm += Ac[dy + 1][dx + 1] * s256p[cr(gy + dy) - R256][cr(gx + dx) - C256];
                }
            val = ctr - sm * inv + r3[(size_t)gy * 512 + gx] * inv;
        }
        s512v[pr][pc] = val;
    }
    __syncthreads();
    // ---- level 1024 patch [10][68] (66 used) ----
    int R10 = 8 * by - 1, C10 = 64 * bx - 1;
    for (int i = t; i < 680; i += 256) {
        int pr = i / 68, pc = i - (i / 68) * 68;
        if (pc < 66) {
            int gy = R10 + pr, gx = C10 + pc;
            float val = 0.f;
            if (gy >= 0 && gy < 1024 && gx >= 0 && gx < 1024) {
                float ctr = s512v[cr(gy) - S5r][cr(gx) - S5c];
                float sm = 0.f;
#pragma unroll
                for (int dy = -1; dy <= 1; ++dy)
#pragma unroll
                    for (int dx = -1; dx <= 1; ++dx) {
                        if (dy == 0 && dx == 0) continue;
                        sm += Ac[dy + 1][dx + 1] *
                              s512v[cr(gy + dy) - S5r][cr(gx + dx) - S5c];
                    }
                val = ctr - sm * inv + bf2f(r2[(size_t)gy * 1024 + gx]) * inv;
            }
            s1024[pr][pc] = val;
        }
    }
    __syncthreads();
    // ---- e2048 in regs (r1 recomputed from v[][]) ----
    float e2[4][2];
    int EY0 = 16 * by + 4 * w, EX0 = 128 * bx + 2 * lane;
#pragma unroll
    for (int a = 0; a < 4; ++a) {
        int gy = EY0 + a;
        float a0 = 0.f, a1 = 0.f;
#pragma unroll
        for (int i = 0; i < 4; ++i) {
            const float* vv = v[2 * a + i];
#pragma unroll
            for (int j = 0; j < 4; ++j) {
                a0 += wt[i][j] * vv[j];
                a1 += wt[i][j] * vv[j + 2];
            }
        }
        float r1v[2] = {0.25f * a0, 0.25f * a1};
#pragma unroll
        for (int b = 0; b < 2; ++b) {
            int gx = EX0 + b;
            float ctr = s1024[(gy >> 1) - R10][(gx >> 1) - C10];
            float sm = 0.f;
#pragma unroll
            for (int dy = -1; dy <= 1; ++dy)
#pragma unroll
                for (int dx = -1; dx <= 1; ++dx) {
                    if (dy == 0 && dx == 0) continue;
                    sm += Ac[dy + 1][dx + 1] *
                          s1024[((gy + dy) >> 1) - R10][((gx + dx) >> 1) - C10];
                }
            e2[a][b] = ctr - sm * inv + r1v[b] * inv;
        }
    }
    // ---- u update ----
    float mn = 3.402823466e+38f, mx = -3.402823466e+38f;
#pragma unroll
    for (int r = 0; r < 8; ++r) {
        int y = yb + r;
        const float* va = v[r];
        const float* vb = v[r + 1];
        const float* vc = v[r + 2];
        float out[4];
#pragma unroll
        for (int c = 0; c < 4; ++c) {
            float sm = Ac[0][0] * va[c] + Ac[0][1] * va[c + 1] + Ac[0][2] * va[c + 2]
                     + Ac[1][0] * vb[c]                        + Ac[1][2] * vb[c + 2]
                     + Ac[2][0] * vc[c] + Ac[2][1] * vc[c + 1] + Ac[2][2] * vc[c + 2];
            out[c] = vb[c + 1] - e2[r >> 1][c >> 1] - sm * inv;
        }
        if constexpr (sizeof(TO) == 4) {
            *(float4*)&uo[(size_t)y * n + xm] =
                make_float4(out[0], out[1], out[2], out[3]);
        } else {
            ushort4 o;
            o.x = f2bf(out[0]); o.y = f2bf(out[1]);
            o.z = f2bf(out[2]); o.w = f2bf(out[3]);
            *(ushort4*)&uo[(size_t)y * n + xm] = o;
        }
        if (WANTMM) {
            mn = fminf(mn, fminf(fminf(out[0], out[1]), fminf(out[2], out[3])));
            mx = fmaxf(mx, fmaxf(fmaxf(out[0], out[1]), fmaxf(out[2], out[3])));
        }
    }
    if (WANTMM) {
#pragma unroll
        for (int off = 32; off > 0; off >>= 1) {
            mn = fminf(mn, __shfl_down(mn, off));
            mx = fmaxf(mx, __shfl_down(mx, off));
        }
        __shared__ float smn[4], smx[4];
        if (lane == 0) { smn[w] = mn; smx[w] = mx; }
        __syncthreads();
        if (t == 0) {
            mn = smn[0]; mx = smx[0];
            for (int wq = 1; wq < 4; ++wq) { mn = fminf(mn, smn[wq]); mx = fmaxf(mx, smx[wq]); }
            int bid = by * 16 + bx;
            partials[2 * bid] = mn;
            partials[2 * bid + 1] = mx;
        }
    }
}

__global__ __launch_bounds__(1024) void minmax_final_kernel(
    const float* __restrict__ partials, float* __restrict__ mm)
{
    float mn = 3.402823466e+38f, mx = -3.402823466e+38f;
    for (int i = threadIdx.x; i < 2048; i += 1024) {
        mn = fminf(mn, partials[2 * i]);
        mx = fmaxf(mx, partials[2 * i + 1]);
    }
#pragma unroll
    for (int off = 32; off > 0; off >>= 1) {
        mn = fminf(mn, __shfl_down(mn, off));
        mx = fmaxf(mx, __shfl_down(mx, off));
    }
    __shared__ float smn[16], smx[16];
    int lane = threadIdx.x & 63, wv = threadIdx.x >> 6;
    if (lane == 0) { smn[wv] = mn; smx[wv] = mx; }
    __syncthreads();
    if (threadIdx.x == 0) {
        mn = smn[0]; mx = smx[0];
        for (int w = 1; w < 16; ++w) { mn = fminf(mn, smn[w]); mx = fmaxf(mx, smx[w]); }
        mm[0] = mn;
        mm[1] = mx;
    }
}

// normalize: read bf16 u, write f32 output
__global__ __launch_bounds__(256) void normalize_kernel(
    const unsigned short* __restrict__ uin, float* __restrict__ uout,
    const float* __restrict__ mm)
{
    size_t i = ((size_t)blockIdx.x * 256 + threadIdx.x) * 4;
    float mn = mm[0];
    float sc = 1.0f / (mm[1] - mm[0]);
    ushort4 h = *(const ushort4*)&uin[i];
    float4 v;
    v.x = (bf2f(h.x) - mn) * sc;
    v.y = (bf2f(h.y) - mn) * sc;
    v.z = (bf2f(h.z) - mn) * sc;
    v.w = (bf2f(h.w) - mn) * sc;
    *(float4*)&uout[i] = v;
}

extern "C" void kernel_launch(void* const* d_in, const int* in_sizes, int n_in,
                              void* d_out, int out_size, void* d_ws, size_t ws_size,
                              hipStream_t stream)
{
    const float* A  = (const float*)d_in[0];
    const float* u0 = (const float*)d_in[1];
    float* uout = (float*)d_out;
    char* ws = (char*)d_ws;

    size_t off = 0;
    auto alloc_f = [&](size_t nelem) { float* p = (float*)(ws + off); off += nelem * 4; return p; };
    float* r3 = alloc_f(512ull * 512);
    float* r4 = alloc_f(256ull * 256);
    float* r5 = alloc_f(128ull * 128);
    float* r6 = alloc_f(64ull * 64);
    float* r7 = alloc_f(32ull * 32);
    float* partials = alloc_f(4096);
    float* mm = alloc_f(2);
    off = (off + 15) & ~15ull;
    unsigned short* r2 = (unsigned short*)(ws + off); off += 1024ull * 1024 * 2;
    off = (off + 15) & ~15ull;
    unsigned short* ubA = (unsigned short*)(ws + off); off += 4096ull * 4096 * 2;
    unsigned short* ubB = (unsigned short*)(ws + off); off += 4096ull * 4096 * 2;

    // it0: u0(f32) -> ubA ; it1: ubA -> ubB ; it2: ubB -> ubA ; it3: ubA -> ubB(bf16)
    for (int it = 0; it < 4; ++it) {
        if (it == 0) {
            smooth_restrict2_kernel<float><<<2048, 256, 0, stream>>>(u0, A, r2, r3);
        } else {
            const unsigned short* us = (it == 2) ? ubB : ubA;
            smooth_restrict2_kernel<unsigned short><<<2048, 256, 0, stream>>>(us, A, r2, r3);
        }
        multirestrict_kernel<<<dim3(16, 16), 256, 0, stream>>>(r3, r4, r5, r6, r7);
        if (it == 0) {
            final_fused_kernel<float, unsigned short, false><<<2048, 256, 0, stream>>>(
                u0, r7, r6, r5, r4, r3, r2, A, ubA, partials);
        } else if (it == 1) {
            final_fused_kernel<unsigned short, unsigned short, false><<<2048, 256, 0, stream>>>(
                ubA, r7, r6, r5, r4, r3, r2, A, ubB, partials);
        } else if (it == 2) {
            final_fused_kernel<unsigned short, unsigned short, false><<<2048, 256, 0, stream>>>(
                ubB, r7, r6, r5, r4, r3, r2, A, ubA, partials);
        } else {
            final_fused_kernel<unsigned short, unsigned short, true><<<2048, 256, 0, stream>>>(
                ubA, r7, r6, r5, r4, r3, r2, A, ubB, partials);
        }
    }
    minmax_final_kernel<<<1, 1024, 0, stream>>>(partials, mm);
    normalize_kernel<<<16384, 256, 0, stream>>>(ubB, uout, mm);
}